// Round 1
// baseline (709.349 us; speedup 1.0000x reference)
//
#include <hip/hip_runtime.h>
#include <hip/hip_bf16.h>

// Problem constants (match reference)
#define E_NUM 8
#define H_DIM 1024
#define F_DIM 4096
#define T_TOK 16384

// Tile config
#define BM 128
#define BN 128
#define BK 64
#define NT 256          // threads per block (4 waves)
#define MT_MAX (T_TOK / BM + E_NUM)   // 136 worst-case M tiles

typedef __attribute__((ext_vector_type(8))) short bf16x8;
typedef __attribute__((ext_vector_type(4))) float f32x4;

__device__ __forceinline__ short f2bf(float f) {
    // round-to-nearest-even fp32 -> bf16 (NaN not expected in this workload)
    unsigned u = __builtin_bit_cast(unsigned, f);
    u += 0x7FFFu + ((u >> 16) & 1u);
    return (short)(u >> 16);
}

// Map linear M-tile index -> (expert, row0, row_end). Returns expert=-1 if
// the tile index is beyond the actual tile count.
__device__ __forceinline__ void tile_map(const int* __restrict__ cnt, int mt,
                                         int& row0, int& rend, int& e_out) {
    int acc = 0, off = 0;
    e_out = -1;
    for (int i = 0; i < E_NUM; ++i) {
        int c = cnt[i];
        int nti = (c + BM - 1) >> 7;
        if (mt < acc + nti) {
            e_out = i;
            row0 = off + (mt - acc) * BM;
            rend = off + c;
            return;
        }
        acc += nti;
        off += c;
    }
}

// ---------------------------------------------------------------------------
// GEMM1: act[t, n] = gelu( sum_k x[t,k] * w1[e, k, n] ), act stored as bf16
// A = x fp32 [T, H], B = w1[e] fp32 [H, F] (row-major, N contiguous)
// ---------------------------------------------------------------------------
__global__ __launch_bounds__(NT)
void gemm1_kernel(const float* __restrict__ X, const float* __restrict__ W1,
                  const int* __restrict__ cnt, short* __restrict__ act) {
    __shared__ short Alds[BM * BK];   // [row][k], XOR-swizzled 16B units
    __shared__ short Blds[BN * BK];   // [n][k] (transposed), XOR-swizzled

    int row0, rend, e;
    tile_map(cnt, blockIdx.y, row0, rend, e);
    if (e < 0) return;

    const int n0 = blockIdx.x * BN;
    const float* W = W1 + (size_t)e * H_DIM * F_DIM;

    const int tid = threadIdx.x;
    const int lane = tid & 63;
    const int w = tid >> 6;
    const int wr = (w >> 1) * 64;   // wave row offset within tile
    const int wc = (w & 1) * 64;    // wave col offset within tile
    const int lr = lane & 15;
    const int lg = lane >> 4;

    // A staging mapping: thread handles rows a_r0 + 32p, k-chunk a_kc (8 elems)
    const int a_r0 = tid >> 3;      // 0..31
    const int a_kc = tid & 7;       // 0..7
    // B staging mapping: thread owns column n=b_n, k-groups of 8
    const int b_n = tid & 127;
    const int b_kg = (tid >> 7) * 8;

    f32x4 acc[4][4];
#pragma unroll
    for (int i = 0; i < 4; ++i)
#pragma unroll
        for (int j = 0; j < 4; ++j) acc[i][j] = (f32x4){0.f, 0.f, 0.f, 0.f};

    const int KT = H_DIM / BK;   // 16
    for (int kt = 0; kt < KT; ++kt) {
        const int k0 = kt * BK;
        // ---- stage A: fp32 -> bf16, [BM][BK] swizzled
#pragma unroll
        for (int p = 0; p < 4; ++p) {
            int r = a_r0 + 32 * p;
            int grow = row0 + r;
            if (grow > T_TOK - 1) grow = T_TOK - 1;   // clamp (masked at store)
            const float* src = X + (size_t)grow * H_DIM + k0 + a_kc * 8;
            f32x4 f0 = *(const f32x4*)src;
            f32x4 f1 = *(const f32x4*)(src + 4);
            bf16x8 v;
            v[0] = f2bf(f0[0]); v[1] = f2bf(f0[1]); v[2] = f2bf(f0[2]); v[3] = f2bf(f0[3]);
            v[4] = f2bf(f1[0]); v[5] = f2bf(f1[1]); v[6] = f2bf(f1[2]); v[7] = f2bf(f1[3]);
            int unit = (r * 8 + a_kc) ^ (r & 7);
            ((bf16x8*)Alds)[unit] = v;
        }
        // ---- stage B transposed: [BN][BK] swizzled
#pragma unroll
        for (int p = 0; p < 4; ++p) {
            int kb = p * 16 + b_kg;   // 0..63 (8-aligned)
            const float* src = W + (size_t)(k0 + kb) * F_DIM + n0 + b_n;
            bf16x8 v;
#pragma unroll
            for (int j = 0; j < 8; ++j) v[j] = f2bf(src[(size_t)j * F_DIM]);
            int unit = (b_n * 8 + (kb >> 3)) ^ (b_n & 7);
            ((bf16x8*)Blds)[unit] = v;
        }
        __syncthreads();
        // ---- compute: 2 K-steps of 32, 16 MFMA each
#pragma unroll
        for (int kk = 0; kk < 2; ++kk) {
            bf16x8 af[4], bfr[4];
#pragma unroll
            for (int fm = 0; fm < 4; ++fm) {
                int r = wr + fm * 16 + lr;
                int unit = (r * 8 + kk * 4 + lg) ^ (r & 7);
                af[fm] = ((bf16x8*)Alds)[unit];
            }
#pragma unroll
            for (int fn = 0; fn < 4; ++fn) {
                int n = wc + fn * 16 + lr;
                int unit = (n * 8 + kk * 4 + lg) ^ (n & 7);
                bfr[fn] = ((bf16x8*)Blds)[unit];
            }
#pragma unroll
            for (int fm = 0; fm < 4; ++fm)
#pragma unroll
                for (int fn = 0; fn < 4; ++fn)
                    acc[fm][fn] = __builtin_amdgcn_mfma_f32_16x16x32_bf16(
                        af[fm], bfr[fn], acc[fm][fn], 0, 0, 0);
        }
        __syncthreads();
    }

    // ---- epilogue: exact gelu, store bf16
#pragma unroll
    for (int fm = 0; fm < 4; ++fm) {
#pragma unroll
        for (int fn = 0; fn < 4; ++fn) {
            int gcol = n0 + wc + fn * 16 + lr;
#pragma unroll
            for (int rr = 0; rr < 4; ++rr) {
                int grow = row0 + wr + fm * 16 + lg * 4 + rr;
                if (grow < rend) {
                    float v = acc[fm][fn][rr];
                    float g = 0.5f * v * (1.0f + erff(v * 0.70710678118654752f));
                    act[(size_t)grow * F_DIM + gcol] = f2bf(g);
                }
            }
        }
    }
}

// ---------------------------------------------------------------------------
// GEMM2: out[t, n] = sum_k act[t,k] * w2[e, k, n]
// A = act bf16 [T, F], B = w2[e] fp32 [F, H] (row-major), out fp32 [T, H]
// ---------------------------------------------------------------------------
__global__ __launch_bounds__(NT)
void gemm2_kernel(const short* __restrict__ ACT, const float* __restrict__ W2,
                  const int* __restrict__ cnt, float* __restrict__ out) {
    __shared__ short Alds[BM * BK];
    __shared__ short Blds[BN * BK];

    int row0, rend, e;
    tile_map(cnt, blockIdx.y, row0, rend, e);
    if (e < 0) return;

    const int n0 = blockIdx.x * BN;
    const float* W = W2 + (size_t)e * F_DIM * H_DIM;

    const int tid = threadIdx.x;
    const int lane = tid & 63;
    const int w = tid >> 6;
    const int wr = (w >> 1) * 64;
    const int wc = (w & 1) * 64;
    const int lr = lane & 15;
    const int lg = lane >> 4;

    const int a_r0 = tid >> 3;
    const int a_kc = tid & 7;
    const int b_n = tid & 127;
    const int b_kg = (tid >> 7) * 8;

    f32x4 acc[4][4];
#pragma unroll
    for (int i = 0; i < 4; ++i)
#pragma unroll
        for (int j = 0; j < 4; ++j) acc[i][j] = (f32x4){0.f, 0.f, 0.f, 0.f};

    const int KT = F_DIM / BK;   // 64
    for (int kt = 0; kt < KT; ++kt) {
        const int k0 = kt * BK;
        // ---- stage A (already bf16): direct 16B copy
#pragma unroll
        for (int p = 0; p < 4; ++p) {
            int r = a_r0 + 32 * p;
            int grow = row0 + r;
            if (grow > T_TOK - 1) grow = T_TOK - 1;
            const short* src = ACT + (size_t)grow * F_DIM + k0 + a_kc * 8;
            bf16x8 v = *(const bf16x8*)src;
            int unit = (r * 8 + a_kc) ^ (r & 7);
            ((bf16x8*)Alds)[unit] = v;
        }
        // ---- stage B transposed
#pragma unroll
        for (int p = 0; p < 4; ++p) {
            int kb = p * 16 + b_kg;
            const float* src = W + (size_t)(k0 + kb) * H_DIM + n0 + b_n;
            bf16x8 v;
#pragma unroll
            for (int j = 0; j < 8; ++j) v[j] = f2bf(src[(size_t)j * H_DIM]);
            int unit = (b_n * 8 + (kb >> 3)) ^ (b_n & 7);
            ((bf16x8*)Blds)[unit] = v;
        }
        __syncthreads();
#pragma unroll
        for (int kk = 0; kk < 2; ++kk) {
            bf16x8 af[4], bfr[4];
#pragma unroll
            for (int fm = 0; fm < 4; ++fm) {
                int r = wr + fm * 16 + lr;
                int unit = (r * 8 + kk * 4 + lg) ^ (r & 7);
                af[fm] = ((bf16x8*)Alds)[unit];
            }
#pragma unroll
            for (int fn = 0; fn < 4; ++fn) {
                int n = wc + fn * 16 + lr;
                int unit = (n * 8 + kk * 4 + lg) ^ (n & 7);
                bfr[fn] = ((bf16x8*)Blds)[unit];
            }
#pragma unroll
            for (int fm = 0; fm < 4; ++fm)
#pragma unroll
                for (int fn = 0; fn < 4; ++fn)
                    acc[fm][fn] = __builtin_amdgcn_mfma_f32_16x16x32_bf16(
                        af[fm], bfr[fn], acc[fm][fn], 0, 0, 0);
        }
        __syncthreads();
    }

#pragma unroll
    for (int fm = 0; fm < 4; ++fm) {
#pragma unroll
        for (int fn = 0; fn < 4; ++fn) {
            int gcol = n0 + wc + fn * 16 + lr;
#pragma unroll
            for (int rr = 0; rr < 4; ++rr) {
                int grow = row0 + wr + fm * 16 + lg * 4 + rr;
                if (grow < rend) {
                    out[(size_t)grow * H_DIM + gcol] = acc[fm][fn][rr];
                }
            }
        }
    }
}

extern "C" void kernel_launch(void* const* d_in, const int* in_sizes, int n_in,
                              void* d_out, int out_size, void* d_ws, size_t ws_size,
                              hipStream_t stream) {
    const float* x  = (const float*)d_in[0];
    const float* w1 = (const float*)d_in[1];
    const float* w2 = (const float*)d_in[2];
    const int* cnt  = (const int*)d_in[3];
    float* out = (float*)d_out;

    // Workspace: act as bf16 [T, F] = 128 MiB
    const size_t act_bytes = (size_t)T_TOK * F_DIM * 2;
    if (ws_size < act_bytes) return;   // clean fail -> signals ws too small
    short* act = (short*)d_ws;

    gemm1_kernel<<<dim3(F_DIM / BN, MT_MAX), NT, 0, stream>>>(x, w1, cnt, act);
    gemm2_kernel<<<dim3(H_DIM / BN, MT_MAX), NT, 0, stream>>>(act, w2, cnt, out);
}

// Round 2
// 630.856 us; speedup vs baseline: 1.1244x; 1.1244x over previous
//
#include <hip/hip_runtime.h>
#include <hip/hip_bf16.h>

// Problem constants (match reference)
#define E_NUM 8
#define H_DIM 1024
#define F_DIM 4096
#define T_TOK 16384

// Tile config
#define BM 128
#define BN 128
#define BK 64
#define NT 256          // threads per block (4 waves)
#define MT_MAX (T_TOK / BM + E_NUM)   // 136 worst-case M tiles

typedef __attribute__((ext_vector_type(8))) short bf16x8;
typedef __attribute__((ext_vector_type(4))) float f32x4;

__device__ __forceinline__ short f2bf(float f) {
    unsigned u = __builtin_bit_cast(unsigned, f);
    u += 0x7FFFu + ((u >> 16) & 1u);
    return (short)(u >> 16);
}

__device__ __forceinline__ void gload16(const void* g, void* l) {
    __builtin_amdgcn_global_load_lds(
        (const __attribute__((address_space(1))) void*)g,
        (__attribute__((address_space(3))) void*)l, 16, 0, 0);
}

// Map linear M-tile index -> (expert, row0, row_end).
__device__ __forceinline__ void tile_map(const int* __restrict__ cnt, int mt,
                                         int& row0, int& rend, int& e_out) {
    int acc = 0, off = 0;
    e_out = -1;
    for (int i = 0; i < E_NUM; ++i) {
        int c = cnt[i];
        int nti = (c + BM - 1) >> 7;
        if (mt < acc + nti) {
            e_out = i;
            row0 = off + (mt - acc) * BM;
            rend = off + c;
            return;
        }
        acc += nti;
        off += c;
    }
}

// ---------------------------------------------------------------------------
// Prep: fp32 -> bf16 elementwise (for x)
// ---------------------------------------------------------------------------
__global__ __launch_bounds__(NT)
void cvt_x_kernel(const float* __restrict__ in, short* __restrict__ out, int n8) {
    int i = blockIdx.x * blockDim.x + threadIdx.x;
    const int stride = gridDim.x * blockDim.x;
    for (; i < n8; i += stride) {
        f32x4 f0 = ((const f32x4*)in)[(size_t)i * 2];
        f32x4 f1 = ((const f32x4*)in)[(size_t)i * 2 + 1];
        bf16x8 v;
        v[0] = f2bf(f0[0]); v[1] = f2bf(f0[1]); v[2] = f2bf(f0[2]); v[3] = f2bf(f0[3]);
        v[4] = f2bf(f1[0]); v[5] = f2bf(f1[1]); v[6] = f2bf(f1[2]); v[7] = f2bf(f1[3]);
        ((bf16x8*)out)[i] = v;
    }
}

// ---------------------------------------------------------------------------
// Prep: per-expert transpose + convert: in fp32 [E][R][C] -> out bf16 [E][C][R]
// ---------------------------------------------------------------------------
__global__ __launch_bounds__(NT)
void transpose_cvt(const float* __restrict__ in, short* __restrict__ out,
                   int R, int C) {
    __shared__ short tb[64][72];   // +8 pad kills bank conflicts
    const int e = blockIdx.z;
    const float* ine = in + (size_t)e * R * C;
    short* oute = out + (size_t)e * R * C;
    const int c0 = blockIdx.x * 64, r0 = blockIdx.y * 64;
    const int t = threadIdx.x;
    const int rl = t >> 4, cl = (t & 15) * 4;
#pragma unroll
    for (int p = 0; p < 4; ++p) {
        int r = rl + p * 16;
        f32x4 f = *(const f32x4*)(ine + (size_t)(r0 + r) * C + c0 + cl);
#pragma unroll
        for (int j = 0; j < 4; ++j) tb[cl + j][r] = f2bf(f[j]);
    }
    __syncthreads();
    const int c2 = t >> 3, rc = (t & 7) * 8;
#pragma unroll
    for (int p = 0; p < 2; ++p) {
        int c = c2 + p * 32;
        bf16x8 v = *(const bf16x8*)&tb[c][rc];
        *(bf16x8*)(oute + (size_t)(c0 + c) * R + r0 + rc) = v;
    }
}

// ---------------------------------------------------------------------------
// Fast grouped GEMM (m97 structure): bf16 A [T][KTOT], bf16 B-transposed
// [E][NCOLS][KTOT]; global_load_lds width-16 staging with pre-swizzled source.
// LDS layout: unit s (16B) holds (r = s>>3, kc = (s&7)^(r&7)) -> conflict-free
// ds_read_b128 fragment reads (same XOR swizzle as round 1, verified 0 confl).
// ---------------------------------------------------------------------------
template<int KTOT, int LDC, bool GELU>
__global__ __launch_bounds__(NT)
void gemm_fast(const short* __restrict__ A, const short* __restrict__ Bw,
               const int* __restrict__ cnt, void* __restrict__ Cout) {
    __shared__ short Alds[BM * BK];
    __shared__ short Blds[BN * BK];

    int row0, rend, e;
    tile_map(cnt, blockIdx.y, row0, rend, e);
    if (e < 0) return;
    const int n0 = blockIdx.x * BN;
    const short* Be = Bw + (size_t)e * ((size_t)F_DIM * H_DIM);

    const int tid = threadIdx.x;
    const int lane = tid & 63;
    const int w = tid >> 6;
    const int wr = (w >> 1) * 64;
    const int wc = (w & 1) * 64;
    const int lr = lane & 15;
    const int lg = lane >> 4;

    // staging: thread handles linear LDS units {p*256 + tid}; source address is
    // inverse-swizzled so swizzled reads see the right data.
    const short* ag[4];
    const short* bg[4];
#pragma unroll
    for (int p = 0; p < 4; ++p) {
        int s = p * 256 + tid;
        int r = s >> 3;
        int kc = (s & 7) ^ (r & 7);
        int grow = row0 + r;
        if (grow >= T_TOK) grow = T_TOK - 1;   // clamp; masked at store
        ag[p] = A + (size_t)grow * KTOT + kc * 8;
        bg[p] = Be + (size_t)(n0 + r) * KTOT + kc * 8;
    }

    f32x4 acc[4][4];
#pragma unroll
    for (int i = 0; i < 4; ++i)
#pragma unroll
        for (int j = 0; j < 4; ++j) acc[i][j] = (f32x4){0.f, 0.f, 0.f, 0.f};

    for (int kt = 0; kt < KTOT / BK; ++kt) {
#pragma unroll
        for (int p = 0; p < 4; ++p) {
            gload16(ag[p], Alds + (p * 256 + tid) * 8);
            gload16(bg[p], Blds + (p * 256 + tid) * 8);
            ag[p] += BK;
            bg[p] += BK;
        }
        __syncthreads();   // compiler drains vmcnt before barrier -> tiles ready
#pragma unroll
        for (int kk = 0; kk < 2; ++kk) {
            bf16x8 af[4], bfr[4];
#pragma unroll
            for (int fm = 0; fm < 4; ++fm) {
                int r = wr + fm * 16 + lr;
                int unit = (r * 8 + kk * 4 + lg) ^ (r & 7);
                af[fm] = ((bf16x8*)Alds)[unit];
            }
#pragma unroll
            for (int fn = 0; fn < 4; ++fn) {
                int n = wc + fn * 16 + lr;
                int unit = (n * 8 + kk * 4 + lg) ^ (n & 7);
                bfr[fn] = ((bf16x8*)Blds)[unit];
            }
#pragma unroll
            for (int fm = 0; fm < 4; ++fm)
#pragma unroll
                for (int fn = 0; fn < 4; ++fn)
                    acc[fm][fn] = __builtin_amdgcn_mfma_f32_16x16x32_bf16(
                        af[fm], bfr[fn], acc[fm][fn], 0, 0, 0);
        }
        __syncthreads();
    }

#pragma unroll
    for (int fm = 0; fm < 4; ++fm) {
#pragma unroll
        for (int fn = 0; fn < 4; ++fn) {
            int gcol = n0 + wc + fn * 16 + lr;
#pragma unroll
            for (int rr = 0; rr < 4; ++rr) {
                int grow = row0 + wr + fm * 16 + lg * 4 + rr;
                if (grow < rend) {
                    float v = acc[fm][fn][rr];
                    if constexpr (GELU) {
                        float g = 0.5f * v * (1.0f + erff(v * 0.70710678118654752f));
                        ((short*)Cout)[(size_t)grow * LDC + gcol] = f2bf(g);
                    } else {
                        ((float*)Cout)[(size_t)grow * LDC + gcol] = v;
                    }
                }
            }
        }
    }
}

// ---------------------------------------------------------------------------
// Round-1 fallback kernels (reg-staged, in-loop conversion) — used only if
// ws_size is too small for the bf16 prep buffers.
// ---------------------------------------------------------------------------
__global__ __launch_bounds__(NT)
void gemm1_kernel(const float* __restrict__ X, const float* __restrict__ W1,
                  const int* __restrict__ cnt, short* __restrict__ act) {
    __shared__ short Alds[BM * BK];
    __shared__ short Blds[BN * BK];

    int row0, rend, e;
    tile_map(cnt, blockIdx.y, row0, rend, e);
    if (e < 0) return;

    const int n0 = blockIdx.x * BN;
    const float* W = W1 + (size_t)e * H_DIM * F_DIM;

    const int tid = threadIdx.x;
    const int lane = tid & 63;
    const int w = tid >> 6;
    const int wr = (w >> 1) * 64;
    const int wc = (w & 1) * 64;
    const int lr = lane & 15;
    const int lg = lane >> 4;

    const int a_r0 = tid >> 3;
    const int a_kc = tid & 7;
    const int b_n = tid & 127;
    const int b_kg = (tid >> 7) * 8;

    f32x4 acc[4][4];
#pragma unroll
    for (int i = 0; i < 4; ++i)
#pragma unroll
        for (int j = 0; j < 4; ++j) acc[i][j] = (f32x4){0.f, 0.f, 0.f, 0.f};

    const int KT = H_DIM / BK;
    for (int kt = 0; kt < KT; ++kt) {
        const int k0 = kt * BK;
#pragma unroll
        for (int p = 0; p < 4; ++p) {
            int r = a_r0 + 32 * p;
            int grow = row0 + r;
            if (grow > T_TOK - 1) grow = T_TOK - 1;
            const float* src = X + (size_t)grow * H_DIM + k0 + a_kc * 8;
            f32x4 f0 = *(const f32x4*)src;
            f32x4 f1 = *(const f32x4*)(src + 4);
            bf16x8 v;
            v[0] = f2bf(f0[0]); v[1] = f2bf(f0[1]); v[2] = f2bf(f0[2]); v[3] = f2bf(f0[3]);
            v[4] = f2bf(f1[0]); v[5] = f2bf(f1[1]); v[6] = f2bf(f1[2]); v[7] = f2bf(f1[3]);
            int unit = (r * 8 + a_kc) ^ (r & 7);
            ((bf16x8*)Alds)[unit] = v;
        }
#pragma unroll
        for (int p = 0; p < 4; ++p) {
            int kb = p * 16 + b_kg;
            const float* src = W + (size_t)(k0 + kb) * F_DIM + n0 + b_n;
            bf16x8 v;
#pragma unroll
            for (int j = 0; j < 8; ++j) v[j] = f2bf(src[(size_t)j * F_DIM]);
            int unit = (b_n * 8 + (kb >> 3)) ^ (b_n & 7);
            ((bf16x8*)Blds)[unit] = v;
        }
        __syncthreads();
#pragma unroll
        for (int kk = 0; kk < 2; ++kk) {
            bf16x8 af[4], bfr[4];
#pragma unroll
            for (int fm = 0; fm < 4; ++fm) {
                int r = wr + fm * 16 + lr;
                int unit = (r * 8 + kk * 4 + lg) ^ (r & 7);
                af[fm] = ((bf16x8*)Alds)[unit];
            }
#pragma unroll
            for (int fn = 0; fn < 4; ++fn) {
                int n = wc + fn * 16 + lr;
                int unit = (n * 8 + kk * 4 + lg) ^ (n & 7);
                bfr[fn] = ((bf16x8*)Blds)[unit];
            }
#pragma unroll
            for (int fm = 0; fm < 4; ++fm)
#pragma unroll
                for (int fn = 0; fn < 4; ++fn)
                    acc[fm][fn] = __builtin_amdgcn_mfma_f32_16x16x32_bf16(
                        af[fm], bfr[fn], acc[fm][fn], 0, 0, 0);
        }
        __syncthreads();
    }

#pragma unroll
    for (int fm = 0; fm < 4; ++fm) {
#pragma unroll
        for (int fn = 0; fn < 4; ++fn) {
            int gcol = n0 + wc + fn * 16 + lr;
#pragma unroll
            for (int rr = 0; rr < 4; ++rr) {
                int grow = row0 + wr + fm * 16 + lg * 4 + rr;
                if (grow < rend) {
                    float v = acc[fm][fn][rr];
                    float g = 0.5f * v * (1.0f + erff(v * 0.70710678118654752f));
                    act[(size_t)grow * F_DIM + gcol] = f2bf(g);
                }
            }
        }
    }
}

__global__ __launch_bounds__(NT)
void gemm2_kernel(const short* __restrict__ ACT, const float* __restrict__ W2,
                  const int* __restrict__ cnt, float* __restrict__ out) {
    __shared__ short Alds[BM * BK];
    __shared__ short Blds[BN * BK];

    int row0, rend, e;
    tile_map(cnt, blockIdx.y, row0, rend, e);
    if (e < 0) return;

    const int n0 = blockIdx.x * BN;
    const float* W = W2 + (size_t)e * F_DIM * H_DIM;

    const int tid = threadIdx.x;
    const int lane = tid & 63;
    const int w = tid >> 6;
    const int wr = (w >> 1) * 64;
    const int wc = (w & 1) * 64;
    const int lr = lane & 15;
    const int lg = lane >> 4;

    const int a_r0 = tid >> 3;
    const int a_kc = tid & 7;
    const int b_n = tid & 127;
    const int b_kg = (tid >> 7) * 8;

    f32x4 acc[4][4];
#pragma unroll
    for (int i = 0; i < 4; ++i)
#pragma unroll
        for (int j = 0; j < 4; ++j) acc[i][j] = (f32x4){0.f, 0.f, 0.f, 0.f};

    const int KT = F_DIM / BK;
    for (int kt = 0; kt < KT; ++kt) {
        const int k0 = kt * BK;
#pragma unroll
        for (int p = 0; p < 4; ++p) {
            int r = a_r0 + 32 * p;
            int grow = row0 + r;
            if (grow > T_TOK - 1) grow = T_TOK - 1;
            const short* src = ACT + (size_t)grow * F_DIM + k0 + a_kc * 8;
            bf16x8 v = *(const bf16x8*)src;
            int unit = (r * 8 + a_kc) ^ (r & 7);
            ((bf16x8*)Alds)[unit] = v;
        }
#pragma unroll
        for (int p = 0; p < 4; ++p) {
            int kb = p * 16 + b_kg;
            const float* src = W + (size_t)(k0 + kb) * H_DIM + n0 + b_n;
            bf16x8 v;
#pragma unroll
            for (int j = 0; j < 8; ++j) v[j] = f2bf(src[(size_t)j * H_DIM]);
            int unit = (b_n * 8 + (kb >> 3)) ^ (b_n & 7);
            ((bf16x8*)Blds)[unit] = v;
        }
        __syncthreads();
#pragma unroll
        for (int kk = 0; kk < 2; ++kk) {
            bf16x8 af[4], bfr[4];
#pragma unroll
            for (int fm = 0; fm < 4; ++fm) {
                int r = wr + fm * 16 + lr;
                int unit = (r * 8 + kk * 4 + lg) ^ (r & 7);
                af[fm] = ((bf16x8*)Alds)[unit];
            }
#pragma unroll
            for (int fn = 0; fn < 4; ++fn) {
                int n = wc + fn * 16 + lr;
                int unit = (n * 8 + kk * 4 + lg) ^ (n & 7);
                bfr[fn] = ((bf16x8*)Blds)[unit];
            }
#pragma unroll
            for (int fm = 0; fm < 4; ++fm)
#pragma unroll
                for (int fn = 0; fn < 4; ++fn)
                    acc[fm][fn] = __builtin_amdgcn_mfma_f32_16x16x32_bf16(
                        af[fm], bfr[fn], acc[fm][fn], 0, 0, 0);
        }
        __syncthreads();
    }

#pragma unroll
    for (int fm = 0; fm < 4; ++fm) {
#pragma unroll
        for (int fn = 0; fn < 4; ++fn) {
            int gcol = n0 + wc + fn * 16 + lr;
#pragma unroll
            for (int rr = 0; rr < 4; ++rr) {
                int grow = row0 + wr + fm * 16 + lg * 4 + rr;
                if (grow < rend) {
                    out[(size_t)grow * H_DIM + gcol] = acc[fm][fn][rr];
                }
            }
        }
    }
}

extern "C" void kernel_launch(void* const* d_in, const int* in_sizes, int n_in,
                              void* d_out, int out_size, void* d_ws, size_t ws_size,
                              hipStream_t stream) {
    const float* x  = (const float*)d_in[0];
    const float* w1 = (const float*)d_in[1];
    const float* w2 = (const float*)d_in[2];
    const int* cnt  = (const int*)d_in[3];
    float* out = (float*)d_out;

    const size_t ACT_B = (size_t)T_TOK * F_DIM * 2;              // 128 MiB
    const size_t WT_B  = (size_t)E_NUM * F_DIM * H_DIM * 2;      //  64 MiB
    const size_t XB_B  = (size_t)T_TOK * H_DIM * 2;              //  32 MiB

    if (ws_size >= ACT_B + WT_B + XB_B) {
        // Fast path: bf16 pre-converted operands + global_load_lds GEMMs.
        short* act = (short*)d_ws;
        short* wt  = (short*)((char*)d_ws + ACT_B);
        short* xb  = (short*)((char*)d_ws + ACT_B + WT_B);

        cvt_x_kernel<<<2048, NT, 0, stream>>>(x, xb, T_TOK * H_DIM / 8);
        // w1 [E][H][F] -> wt [E][F][H]
        transpose_cvt<<<dim3(F_DIM / 64, H_DIM / 64, E_NUM), NT, 0, stream>>>(
            w1, wt, H_DIM, F_DIM);
        gemm_fast<H_DIM, F_DIM, true><<<dim3(F_DIM / BN, MT_MAX), NT, 0, stream>>>(
            xb, wt, cnt, (void*)act);
        // w2 [E][F][H] -> wt [E][H][F] (reuses wt; stream-ordered after gemm1)
        transpose_cvt<<<dim3(H_DIM / 64, F_DIM / 64, E_NUM), NT, 0, stream>>>(
            w2, wt, F_DIM, H_DIM);
        gemm_fast<F_DIM, H_DIM, false><<<dim3(H_DIM / BN, MT_MAX), NT, 0, stream>>>(
            act, wt, cnt, (void*)out);
    } else if (ws_size >= ACT_B) {
        // Fallback: round-1 verified kernels.
        short* act = (short*)d_ws;
        gemm1_kernel<<<dim3(F_DIM / BN, MT_MAX), NT, 0, stream>>>(x, w1, cnt, act);
        gemm2_kernel<<<dim3(H_DIM / BN, MT_MAX), NT, 0, stream>>>(act, w2, cnt, out);
    }
}

// Round 4
// 486.542 us; speedup vs baseline: 1.4579x; 1.2966x over previous
//
#include <hip/hip_runtime.h>
#include <hip/hip_bf16.h>

// Problem constants (match reference)
#define E_NUM 8
#define H_DIM 1024
#define F_DIM 4096
#define T_TOK 16384

#define NT 256
#define MT_MAX (T_TOK / 128 + E_NUM)    // 136 worst-case 128-row M tiles (fallback)
#define MT256 (T_TOK / 256 + E_NUM)     // 72 worst-case 256-row M tiles

typedef __attribute__((ext_vector_type(8))) short bf16x8;
typedef __attribute__((ext_vector_type(4))) float f32x4;

__device__ __forceinline__ short f2bf(float f) {
    unsigned u = __builtin_bit_cast(unsigned, f);
    u += 0x7FFFu + ((u >> 16) & 1u);
    return (short)(u >> 16);
}

__device__ __forceinline__ float exp2_fast(float a) {
#if __has_builtin(__builtin_amdgcn_exp2f)
    return __builtin_amdgcn_exp2f(a);
#else
    return exp2f(a);
#endif
}
__device__ __forceinline__ float rcp_fast(float a) {
#if __has_builtin(__builtin_amdgcn_rcpf)
    return __builtin_amdgcn_rcpf(a);
#else
    return 1.0f / a;
#endif
}

// tanh-form gelu: max |err| vs exact ~1e-3 (negligible vs bf16 noise)
__device__ __forceinline__ float fast_gelu(float x) {
    float x2 = x * x;
    float y = x * (0.7978845608f + 0.0356774081f * x2);
    float z = exp2_fast(y * 2.8853900817779268f);   // e^{2y}
    float r = rcp_fast(z + 1.0f);
    return x * (1.0f - r);
}

__device__ __forceinline__ void gload16(const void* g, void* l) {
    __builtin_amdgcn_global_load_lds(
        (const __attribute__((address_space(1))) void*)g,
        (__attribute__((address_space(3))) void*)l, 16, 0, 0);
}

template<int N>
__device__ __forceinline__ void vmwait() {
    if constexpr (N == 0) asm volatile("s_waitcnt vmcnt(0)" ::: "memory");
    else if constexpr (N == 1) asm volatile("s_waitcnt vmcnt(1)" ::: "memory");
    else if constexpr (N == 2) asm volatile("s_waitcnt vmcnt(2)" ::: "memory");
    else if constexpr (N == 3) asm volatile("s_waitcnt vmcnt(3)" ::: "memory");
    else if constexpr (N == 4) asm volatile("s_waitcnt vmcnt(4)" ::: "memory");
}

// raw barrier with compiler memory-ordering (no waitcnt insertion)
__device__ __forceinline__ void bar() {
    asm volatile("s_barrier" ::: "memory");
}

__device__ __forceinline__ void tile_map128(const int* __restrict__ cnt, int mt,
                                            int& row0, int& rend, int& e_out) {
    int acc = 0, off = 0;
    e_out = -1;
    for (int i = 0; i < E_NUM; ++i) {
        int c = cnt[i];
        int nti = (c + 127) >> 7;
        if (mt < acc + nti) {
            e_out = i; row0 = off + (mt - acc) * 128; rend = off + c; return;
        }
        acc += nti; off += c;
    }
}

__device__ __forceinline__ void tile_map256(const int* __restrict__ cnt, int mt,
                                            int& row0, int& rend, int& e_out) {
    int acc = 0, off = 0;
    e_out = -1;
    for (int i = 0; i < E_NUM; ++i) {
        int c = cnt[i];
        int nti = (c + 255) >> 8;
        if (mt < acc + nti) {
            e_out = i; row0 = off + (mt - acc) * 256; rend = off + c; return;
        }
        acc += nti; off += c;
    }
}

// ---------------------------------------------------------------------------
// Prep kernels
// ---------------------------------------------------------------------------
__global__ __launch_bounds__(NT)
void cvt_x_kernel(const float* __restrict__ in, short* __restrict__ out, int n8) {
    int i = blockIdx.x * blockDim.x + threadIdx.x;
    const int stride = gridDim.x * blockDim.x;
    for (; i < n8; i += stride) {
        f32x4 f0 = ((const f32x4*)in)[(size_t)i * 2];
        f32x4 f1 = ((const f32x4*)in)[(size_t)i * 2 + 1];
        bf16x8 v;
        v[0] = f2bf(f0[0]); v[1] = f2bf(f0[1]); v[2] = f2bf(f0[2]); v[3] = f2bf(f0[3]);
        v[4] = f2bf(f1[0]); v[5] = f2bf(f1[1]); v[6] = f2bf(f1[2]); v[7] = f2bf(f1[3]);
        ((bf16x8*)out)[i] = v;
    }
}

__global__ __launch_bounds__(NT)
void transpose_cvt(const float* __restrict__ in, short* __restrict__ out,
                   int R, int C) {
    __shared__ short tb[64][72];
    const int e = blockIdx.z;
    const float* ine = in + (size_t)e * R * C;
    short* oute = out + (size_t)e * R * C;
    const int c0 = blockIdx.x * 64, r0 = blockIdx.y * 64;
    const int t = threadIdx.x;
    const int rl = t >> 4, cl = (t & 15) * 4;
#pragma unroll
    for (int p = 0; p < 4; ++p) {
        int r = rl + p * 16;
        f32x4 f = *(const f32x4*)(ine + (size_t)(r0 + r) * C + c0 + cl);
#pragma unroll
        for (int j = 0; j < 4; ++j) tb[cl + j][r] = f2bf(f[j]);
    }
    __syncthreads();
    const int c2 = t >> 3, rc = (t & 7) * 8;
#pragma unroll
    for (int p = 0; p < 2; ++p) {
        int c = c2 + p * 32;
        bf16x8 v = *(const bf16x8*)&tb[c][rc];
        *(bf16x8*)(oute + (size_t)(c0 + c) * R + r0 + rc) = v;
    }
}

// ---------------------------------------------------------------------------
// 8-wave 4-phase/K-tile grouped GEMM, BM=256, counted vmcnt in the main loop
// (never drains to 0 mid-loop); final K-tile PEELED with a vmcnt(0) drain —
// the counted values are only valid when the next tile's prefetch is issued.
// A [T][KTOT] bf16, B [E][rows][KTOT] bf16 (K contiguous).
// LDS XOR swizzle: unit(r,kc) = (r*8+kc)^(r&7), staged via inverse-swizzled
// global source + linear global_load_lds dest (both-sides rule).
// ---------------------------------------------------------------------------
#define G8P_READ_A(mh)                                                        \
    _Pragma("unroll") for (int f = 0; f < MF / 2; ++f) {                      \
        const int r_ = ((mh) * (MF / 2) + f) * (16 * WM) + wm * 16 + lr;      \
        _Pragma("unroll") for (int kk = 0; kk < 2; ++kk) {                    \
            const int u_ = (r_ * 8 + kk * 4 + lg) ^ (r_ & 7);                 \
            areg[f][kk] = ((const bf16x8*)Ac)[u_];                            \
        }                                                                     \
    }

#define G8P_READ_B(nh)                                                        \
    _Pragma("unroll") for (int g = 0; g < NF / 2; ++g) {                      \
        const int r_ = ((nh) * (NF / 2) + g) * (16 * WN) + wn * 16 + lr;      \
        _Pragma("unroll") for (int kk = 0; kk < 2; ++kk) {                    \
            const int u_ = (r_ * 8 + kk * 4 + lg) ^ (r_ & 7);                 \
            breg[(nh) * (NF / 2) + g][kk] = ((const bf16x8*)Bc)[u_];          \
        }                                                                     \
    }

#define G8P_QUAD(mh, nh)                                                      \
    _Pragma("unroll") for (int f = 0; f < MF / 2; ++f)                        \
    _Pragma("unroll") for (int g = 0; g < NF / 2; ++g)                        \
    _Pragma("unroll") for (int kk = 0; kk < 2; ++kk)                          \
        acc[(mh) * (MF / 2) + f][(nh) * (NF / 2) + g] =                       \
            __builtin_amdgcn_mfma_f32_16x16x32_bf16(                          \
                areg[f][kk], breg[(nh) * (NF / 2) + g][kk],                   \
                acc[(mh) * (MF / 2) + f][(nh) * (NF / 2) + g], 0, 0, 0);

template<int BN, int WM, int WN, bool GELU, int LDC, int NTX, int KTOT>
__global__ __launch_bounds__(512, 2)
void gemm8p(const short* __restrict__ A, const short* __restrict__ Bw,
            const int* __restrict__ cnt, void* __restrict__ Cout) {
    constexpr int MF = 256 / WM / 16;      // m-frags per wave
    constexpr int NF = BN / WN / 16;       // n-frags per wave
    constexpr int B_P = BN / 64;           // B gload16 per thread per K-tile
    constexpr int A_SH = 16384;            // shorts per A tile
    constexpr int SEG = (256 + BN) * 64;   // shorts per LDS buffer
    constexpr int KT = KTOT / 64;
    constexpr int VM_END = (B_P == 4) ? 4 : 3;   // leaves next A-h1+B-h1 in flight

    __shared__ __align__(16) short lds[2 * SEG];

    // bijective XCD swizzle (grid = NTX*MT256, divisible by 8)
    const int lin = blockIdx.x;
    constexpr int CPX = (NTX * MT256) / 8;
    const int wg = (lin & 7) * CPX + (lin >> 3);
    const int mt = wg / NTX;
    const int nt = wg - mt * NTX;

    int row0, rend, e;
    tile_map256(cnt, mt, row0, rend, e);
    if (e < 0) return;
    const int n0 = nt * BN;
    const short* Be = Bw + (size_t)e * ((size_t)F_DIM * H_DIM);

    const int tid = threadIdx.x;
    const int lane = tid & 63;
    const int lr = lane & 15;
    const int lg = lane >> 4;
    const int w = tid >> 6;
    const int wm = w / WN;
    const int wn = w % WN;

    // inverse-swizzled staging sources
    const short* ag[4];
    const short* bg[B_P];
#pragma unroll
    for (int p = 0; p < 4; ++p) {
        int s = p * 512 + tid;
        int r = s >> 3;
        int kc = (s & 7) ^ (r & 7);
        int grow = row0 + r;
        if (grow >= T_TOK) grow = T_TOK - 1;
        ag[p] = A + (size_t)grow * KTOT + kc * 8;
    }
#pragma unroll
    for (int p = 0; p < B_P; ++p) {
        int s = p * 512 + tid;
        int r = s >> 3;
        int kc = (s & 7) ^ (r & 7);
        bg[p] = Be + (size_t)(n0 + r) * KTOT + kc * 8;
    }

    f32x4 acc[MF][NF];
#pragma unroll
    for (int i = 0; i < MF; ++i)
#pragma unroll
        for (int j = 0; j < NF; ++j) acc[i][j] = (f32x4){0.f, 0.f, 0.f, 0.f};
    bf16x8 areg[MF / 2][2];
    bf16x8 breg[NF][2];

    // ---- prologue: stage tile 0 into buf0, FIFO = [Ah0, Bh0, Ah1, Bh1]
    {
        short* An = lds;
        short* Bn = lds + A_SH;
        gload16(ag[0], An + (0 * 512 + tid) * 8); ag[0] += 64;
        gload16(ag[1], An + (1 * 512 + tid) * 8); ag[1] += 64;
        gload16(bg[0], Bn + (0 * 512 + tid) * 8); bg[0] += 64;
        if constexpr (B_P == 4) { gload16(bg[1], Bn + (1 * 512 + tid) * 8); bg[1] += 64; }
        gload16(ag[2], An + (2 * 512 + tid) * 8); ag[2] += 64;
        gload16(ag[3], An + (3 * 512 + tid) * 8); ag[3] += 64;
        if constexpr (B_P == 4) {
            gload16(bg[2], Bn + (2 * 512 + tid) * 8); bg[2] += 64;
            gload16(bg[3], Bn + (3 * 512 + tid) * 8); bg[3] += 64;
        } else {
            gload16(bg[1], Bn + (1 * 512 + tid) * 8); bg[1] += 64;
        }
    }
    vmwait<VM_END>();
    bar();

    int cur = 0;
    // Main loop: always prefetches the next tile -> counted waits are exact.
    for (int kt = 0; kt < KT - 1; ++kt) {
        const short* Ac = lds + cur * SEG;
        const short* Bc = Ac + A_SH;
        short* An = lds + (cur ^ 1) * SEG;
        short* Bn = An + A_SH;

        // ---- P1: read (m0,n0) frags; issue next A-h0
        G8P_READ_A(0)
        G8P_READ_B(0)
        gload16(ag[0], An + (0 * 512 + tid) * 8); ag[0] += 64;
        gload16(ag[1], An + (1 * 512 + tid) * 8); ag[1] += 64;
        bar();
        __builtin_amdgcn_s_setprio(1);
        G8P_QUAD(0, 0)
        __builtin_amdgcn_s_setprio(0);

        // ---- P2: counted wait retires this tile's A-h1+B-h1; issue next B-h0
        vmwait<2>();
        bar();
        G8P_READ_B(1)
        gload16(bg[0], Bn + (0 * 512 + tid) * 8); bg[0] += 64;
        if constexpr (B_P == 4) { gload16(bg[1], Bn + (1 * 512 + tid) * 8); bg[1] += 64; }
        bar();
        __builtin_amdgcn_s_setprio(1);
        G8P_QUAD(0, 1)
        __builtin_amdgcn_s_setprio(0);

        // ---- P3: A-h1 guaranteed by P2's wait+barrier; issue next A-h1
        G8P_READ_A(1)
        gload16(ag[2], An + (2 * 512 + tid) * 8); ag[2] += 64;
        gload16(ag[3], An + (3 * 512 + tid) * 8); ag[3] += 64;
        bar();
        __builtin_amdgcn_s_setprio(1);
        G8P_QUAD(1, 1)
        __builtin_amdgcn_s_setprio(0);

        // ---- P4: issue next B-h1; end-of-iter counted wait (next Ah0+Bh0 done)
        if constexpr (B_P == 4) {
            gload16(bg[2], Bn + (2 * 512 + tid) * 8); bg[2] += 64;
            gload16(bg[3], Bn + (3 * 512 + tid) * 8); bg[3] += 64;
        } else {
            gload16(bg[1], Bn + (1 * 512 + tid) * 8); bg[1] += 64;
        }
        bar();
        __builtin_amdgcn_s_setprio(1);
        G8P_QUAD(1, 0)
        __builtin_amdgcn_s_setprio(0);
        vmwait<VM_END>();
        bar();
        cur ^= 1;
    }

    // ---- peeled final K-tile: no prefetch; full drain before h1 halves
    {
        const short* Ac = lds + cur * SEG;
        const short* Bc = Ac + A_SH;
        G8P_READ_A(0)
        G8P_READ_B(0)
        G8P_QUAD(0, 0)
        vmwait<0>();           // drain this tile's in-flight A-h1/B-h1
        bar();
        G8P_READ_B(1)
        G8P_QUAD(0, 1)
        G8P_READ_A(1)
        G8P_QUAD(1, 1)
        G8P_QUAD(1, 0)
    }

    // ---- epilogue
#pragma unroll
    for (int f = 0; f < MF; ++f) {
#pragma unroll
        for (int g = 0; g < NF; ++g) {
            const int gcol = n0 + g * (16 * WN) + wn * 16 + lr;
#pragma unroll
            for (int rr = 0; rr < 4; ++rr) {
                const int grow = row0 + f * (16 * WM) + wm * 16 + lg * 4 + rr;
                if (grow < rend) {
                    float v = acc[f][g][rr];
                    if constexpr (GELU) {
                        ((short*)Cout)[(size_t)grow * LDC + gcol] = f2bf(fast_gelu(v));
                    } else {
                        ((float*)Cout)[(size_t)grow * LDC + gcol] = v;
                    }
                }
            }
        }
    }
}

// ---------------------------------------------------------------------------
// Round-1 fallback kernels (only used if ws too small for bf16 prep buffers)
// ---------------------------------------------------------------------------
__global__ __launch_bounds__(NT)
void gemm1_kernel(const float* __restrict__ X, const float* __restrict__ W1,
                  const int* __restrict__ cnt, short* __restrict__ act) {
    __shared__ short Alds[128 * 64];
    __shared__ short Blds[128 * 64];

    int row0, rend, e;
    tile_map128(cnt, blockIdx.y, row0, rend, e);
    if (e < 0) return;

    const int n0 = blockIdx.x * 128;
    const float* W = W1 + (size_t)e * H_DIM * F_DIM;

    const int tid = threadIdx.x;
    const int lane = tid & 63;
    const int w = tid >> 6;
    const int wr = (w >> 1) * 64;
    const int wc = (w & 1) * 64;
    const int lr = lane & 15;
    const int lg = lane >> 4;

    const int a_r0 = tid >> 3;
    const int a_kc = tid & 7;
    const int b_n = tid & 127;
    const int b_kg = (tid >> 7) * 8;

    f32x4 acc[4][4];
#pragma unroll
    for (int i = 0; i < 4; ++i)
#pragma unroll
        for (int j = 0; j < 4; ++j) acc[i][j] = (f32x4){0.f, 0.f, 0.f, 0.f};

    for (int kt = 0; kt < H_DIM / 64; ++kt) {
        const int k0 = kt * 64;
#pragma unroll
        for (int p = 0; p < 4; ++p) {
            int r = a_r0 + 32 * p;
            int grow = row0 + r;
            if (grow > T_TOK - 1) grow = T_TOK - 1;
            const float* src = X + (size_t)grow * H_DIM + k0 + a_kc * 8;
            f32x4 f0 = *(const f32x4*)src;
            f32x4 f1 = *(const f32x4*)(src + 4);
            bf16x8 v;
            v[0] = f2bf(f0[0]); v[1] = f2bf(f0[1]); v[2] = f2bf(f0[2]); v[3] = f2bf(f0[3]);
            v[4] = f2bf(f1[0]); v[5] = f2bf(f1[1]); v[6] = f2bf(f1[2]); v[7] = f2bf(f1[3]);
            ((bf16x8*)Alds)[(r * 8 + a_kc) ^ (r & 7)] = v;
        }
#pragma unroll
        for (int p = 0; p < 4; ++p) {
            int kb = p * 16 + b_kg;
            const float* src = W + (size_t)(k0 + kb) * F_DIM + n0 + b_n;
            bf16x8 v;
#pragma unroll
            for (int j = 0; j < 8; ++j) v[j] = f2bf(src[(size_t)j * F_DIM]);
            ((bf16x8*)Blds)[(b_n * 8 + (kb >> 3)) ^ (b_n & 7)] = v;
        }
        __syncthreads();
#pragma unroll
        for (int kk = 0; kk < 2; ++kk) {
            bf16x8 af[4], bfr[4];
#pragma unroll
            for (int fm = 0; fm < 4; ++fm) {
                int r = wr + fm * 16 + lr;
                af[fm] = ((bf16x8*)Alds)[(r * 8 + kk * 4 + lg) ^ (r & 7)];
            }
#pragma unroll
            for (int fn = 0; fn < 4; ++fn) {
                int n = wc + fn * 16 + lr;
                bfr[fn] = ((bf16x8*)Blds)[(n * 8 + kk * 4 + lg) ^ (n & 7)];
            }
#pragma unroll
            for (int fm = 0; fm < 4; ++fm)
#pragma unroll
                for (int fn = 0; fn < 4; ++fn)
                    acc[fm][fn] = __builtin_amdgcn_mfma_f32_16x16x32_bf16(
                        af[fm], bfr[fn], acc[fm][fn], 0, 0, 0);
        }
        __syncthreads();
    }

#pragma unroll
    for (int fm = 0; fm < 4; ++fm)
#pragma unroll
        for (int fn = 0; fn < 4; ++fn) {
            int gcol = n0 + wc + fn * 16 + lr;
#pragma unroll
            for (int rr = 0; rr < 4; ++rr) {
                int grow = row0 + wr + fm * 16 + lg * 4 + rr;
                if (grow < rend)
                    act[(size_t)grow * F_DIM + gcol] = f2bf(fast_gelu(acc[fm][fn][rr]));
            }
        }
}

__global__ __launch_bounds__(NT)
void gemm2_kernel(const short* __restrict__ ACT, const float* __restrict__ W2,
                  const int* __restrict__ cnt, float* __restrict__ out) {
    __shared__ short Alds[128 * 64];
    __shared__ short Blds[128 * 64];

    int row0, rend, e;
    tile_map128(cnt, blockIdx.y, row0, rend, e);
    if (e < 0) return;

    const int n0 = blockIdx.x * 128;
    const float* W = W2 + (size_t)e * F_DIM * H_DIM;

    const int tid = threadIdx.x;
    const int lane = tid & 63;
    const int w = tid >> 6;
    const int wr = (w >> 1) * 64;
    const int wc = (w & 1) * 64;
    const int lr = lane & 15;
    const int lg = lane >> 4;

    const int a_r0 = tid >> 3;
    const int a_kc = tid & 7;
    const int b_n = tid & 127;
    const int b_kg = (tid >> 7) * 8;

    f32x4 acc[4][4];
#pragma unroll
    for (int i = 0; i < 4; ++i)
#pragma unroll
        for (int j = 0; j < 4; ++j) acc[i][j] = (f32x4){0.f, 0.f, 0.f, 0.f};

    for (int kt = 0; kt < F_DIM / 64; ++kt) {
        const int k0 = kt * 64;
#pragma unroll
        for (int p = 0; p < 4; ++p) {
            int r = a_r0 + 32 * p;
            int grow = row0 + r;
            if (grow > T_TOK - 1) grow = T_TOK - 1;
            bf16x8 v = *(const bf16x8*)(ACT + (size_t)grow * F_DIM + k0 + a_kc * 8);
            ((bf16x8*)Alds)[(r * 8 + a_kc) ^ (r & 7)] = v;
        }
#pragma unroll
        for (int p = 0; p < 4; ++p) {
            int kb = p * 16 + b_kg;
            const float* src = W + (size_t)(k0 + kb) * H_DIM + n0 + b_n;
            bf16x8 v;
#pragma unroll
            for (int j = 0; j < 8; ++j) v[j] = f2bf(src[(size_t)j * H_DIM]);
            ((bf16x8*)Blds)[(b_n * 8 + (kb >> 3)) ^ (b_n & 7)] = v;
        }
        __syncthreads();
#pragma unroll
        for (int kk = 0; kk < 2; ++kk) {
            bf16x8 af[4], bfr[4];
#pragma unroll
            for (int fm = 0; fm < 4; ++fm) {
                int r = wr + fm * 16 + lr;
                af[fm] = ((bf16x8*)Alds)[(r * 8 + kk * 4 + lg) ^ (r & 7)];
            }
#pragma unroll
            for (int fn = 0; fn < 4; ++fn) {
                int n = wc + fn * 16 + lr;
                bfr[fn] = ((bf16x8*)Blds)[(n * 8 + kk * 4 + lg) ^ (n & 7)];
            }
#pragma unroll
            for (int fm = 0; fm < 4; ++fm)
#pragma unroll
                for (int fn = 0; fn < 4; ++fn)
                    acc[fm][fn] = __builtin_amdgcn_mfma_f32_16x16x32_bf16(
                        af[fm], bfr[fn], acc[fm][fn], 0, 0, 0);
        }
        __syncthreads();
    }

#pragma unroll
    for (int fm = 0; fm < 4; ++fm)
#pragma unroll
        for (int fn = 0; fn < 4; ++fn) {
            int gcol = n0 + wc + fn * 16 + lr;
#pragma unroll
            for (int rr = 0; rr < 4; ++rr) {
                int grow = row0 + wr + fm * 16 + lg * 4 + rr;
                if (grow < rend) out[(size_t)grow * H_DIM + gcol] = acc[fm][fn][rr];
            }
        }
}

extern "C" void kernel_launch(void* const* d_in, const int* in_sizes, int n_in,
                              void* d_out, int out_size, void* d_ws, size_t ws_size,
                              hipStream_t stream) {
    const float* x  = (const float*)d_in[0];
    const float* w1 = (const float*)d_in[1];
    const float* w2 = (const float*)d_in[2];
    const int* cnt  = (const int*)d_in[3];
    float* out = (float*)d_out;

    const size_t ACT_B = (size_t)T_TOK * F_DIM * 2;              // 128 MiB
    const size_t WT_B  = (size_t)E_NUM * F_DIM * H_DIM * 2;      //  64 MiB
    const size_t XB_B  = (size_t)T_TOK * H_DIM * 2;              //  32 MiB

    if (ws_size >= ACT_B + WT_B + XB_B) {
        short* act = (short*)d_ws;
        short* wt  = (short*)((char*)d_ws + ACT_B);
        short* xb  = (short*)((char*)d_ws + ACT_B + WT_B);

        cvt_x_kernel<<<2048, NT, 0, stream>>>(x, xb, T_TOK * H_DIM / 8);
        transpose_cvt<<<dim3(F_DIM / 64, H_DIM / 64, E_NUM), NT, 0, stream>>>(
            w1, wt, H_DIM, F_DIM);
        gemm8p<256, 2, 4, true, F_DIM, 16, H_DIM>
            <<<16 * MT256, 512, 0, stream>>>(xb, wt, cnt, (void*)act);
        transpose_cvt<<<dim3(H_DIM / 64, F_DIM / 64, E_NUM), NT, 0, stream>>>(
            w2, wt, F_DIM, H_DIM);
        gemm8p<128, 4, 2, false, H_DIM, 8, F_DIM>
            <<<8 * MT256, 512, 0, stream>>>(act, wt, cnt, (void*)out);
    } else if (ws_size >= ACT_B) {
        short* act = (short*)d_ws;
        gemm1_kernel<<<dim3(F_DIM / 128, MT_MAX), NT, 0, stream>>>(x, w1, cnt, act);
        gemm2_kernel<<<dim3(H_DIM / 128, MT_MAX), NT, 0, stream>>>(act, w2, cnt, out);
    }
}

// Round 5
// 475.305 us; speedup vs baseline: 1.4924x; 1.0236x over previous
//
#include <hip/hip_runtime.h>
#include <hip/hip_bf16.h>

// Problem constants (match reference)
#define E_NUM 8
#define H_DIM 1024
#define F_DIM 4096
#define T_TOK 16384

#define NT 256
#define MT_MAX (T_TOK / 128 + E_NUM)    // 136 worst-case 128-row M tiles (fallback)
#define MT256 (T_TOK / 256 + E_NUM)     // 72 worst-case 256-row M tiles

typedef __attribute__((ext_vector_type(8))) short bf16x8;
typedef __attribute__((ext_vector_type(4))) float f32x4;

__device__ __forceinline__ short f2bf(float f) {
    unsigned u = __builtin_bit_cast(unsigned, f);
    u += 0x7FFFu + ((u >> 16) & 1u);
    return (short)(u >> 16);
}

__device__ __forceinline__ float exp2_fast(float a) {
#if __has_builtin(__builtin_amdgcn_exp2f)
    return __builtin_amdgcn_exp2f(a);
#else
    return exp2f(a);
#endif
}
__device__ __forceinline__ float rcp_fast(float a) {
#if __has_builtin(__builtin_amdgcn_rcpf)
    return __builtin_amdgcn_rcpf(a);
#else
    return 1.0f / a;
#endif
}

// tanh-form gelu: max |err| vs exact ~1e-3 (negligible vs bf16 noise)
__device__ __forceinline__ float fast_gelu(float x) {
    float x2 = x * x;
    float y = x * (0.7978845608f + 0.0356774081f * x2);
    float z = exp2_fast(y * 2.8853900817779268f);   // e^{2y}
    float r = rcp_fast(z + 1.0f);
    return x * (1.0f - r);
}

__device__ __forceinline__ void gload16(const void* g, void* l) {
    __builtin_amdgcn_global_load_lds(
        (const __attribute__((address_space(1))) void*)g,
        (__attribute__((address_space(3))) void*)l, 16, 0, 0);
}

template<int N>
__device__ __forceinline__ void vmwait() {
    if constexpr (N == 0) asm volatile("s_waitcnt vmcnt(0)" ::: "memory");
    else if constexpr (N == 1) asm volatile("s_waitcnt vmcnt(1)" ::: "memory");
    else if constexpr (N == 2) asm volatile("s_waitcnt vmcnt(2)" ::: "memory");
    else if constexpr (N == 3) asm volatile("s_waitcnt vmcnt(3)" ::: "memory");
    else if constexpr (N == 4) asm volatile("s_waitcnt vmcnt(4)" ::: "memory");
}

// raw barrier with compiler memory-ordering (no waitcnt insertion)
__device__ __forceinline__ void bar() {
    asm volatile("s_barrier" ::: "memory");
}

__device__ __forceinline__ void tile_map128(const int* __restrict__ cnt, int mt,
                                            int& row0, int& rend, int& e_out) {
    int acc = 0, off = 0;
    e_out = -1;
    for (int i = 0; i < E_NUM; ++i) {
        int c = cnt[i];
        int nti = (c + 127) >> 7;
        if (mt < acc + nti) {
            e_out = i; row0 = off + (mt - acc) * 128; rend = off + c; return;
        }
        acc += nti; off += c;
    }
}

__device__ __forceinline__ void tile_map256(const int* __restrict__ cnt, int mt,
                                            int& row0, int& rend, int& e_out) {
    int acc = 0, off = 0;
    e_out = -1;
    for (int i = 0; i < E_NUM; ++i) {
        int c = cnt[i];
        int nti = (c + 255) >> 8;
        if (mt < acc + nti) {
            e_out = i; row0 = off + (mt - acc) * 256; rend = off + c; return;
        }
        acc += nti; off += c;
    }
}

// ---------------------------------------------------------------------------
// Prep kernels
// ---------------------------------------------------------------------------
__global__ __launch_bounds__(NT)
void cvt_x_kernel(const float* __restrict__ in, short* __restrict__ out, int n8) {
    int i = blockIdx.x * blockDim.x + threadIdx.x;
    const int stride = gridDim.x * blockDim.x;
    for (; i < n8; i += stride) {
        f32x4 f0 = ((const f32x4*)in)[(size_t)i * 2];
        f32x4 f1 = ((const f32x4*)in)[(size_t)i * 2 + 1];
        bf16x8 v;
        v[0] = f2bf(f0[0]); v[1] = f2bf(f0[1]); v[2] = f2bf(f0[2]); v[3] = f2bf(f0[3]);
        v[4] = f2bf(f1[0]); v[5] = f2bf(f1[1]); v[6] = f2bf(f1[2]); v[7] = f2bf(f1[3]);
        ((bf16x8*)out)[i] = v;
    }
}

__global__ __launch_bounds__(NT)
void transpose_cvt(const float* __restrict__ in, short* __restrict__ out,
                   int R, int C) {
    __shared__ short tb[64][72];
    const int e = blockIdx.z;
    const float* ine = in + (size_t)e * R * C;
    short* oute = out + (size_t)e * R * C;
    const int c0 = blockIdx.x * 64, r0 = blockIdx.y * 64;
    const int t = threadIdx.x;
    const int rl = t >> 4, cl = (t & 15) * 4;
#pragma unroll
    for (int p = 0; p < 4; ++p) {
        int r = rl + p * 16;
        f32x4 f = *(const f32x4*)(ine + (size_t)(r0 + r) * C + c0 + cl);
#pragma unroll
        for (int j = 0; j < 4; ++j) tb[cl + j][r] = f2bf(f[j]);
    }
    __syncthreads();
    const int c2 = t >> 3, rc = (t & 7) * 8;
#pragma unroll
    for (int p = 0; p < 2; ++p) {
        int c = c2 + p * 32;
        bf16x8 v = *(const bf16x8*)&tb[c][rc];
        *(bf16x8*)(oute + (size_t)(c0 + c) * R + r0 + rc) = v;
    }
}

// ---------------------------------------------------------------------------
// 8-wave grouped GEMM, 256x256 tile, BK=64, 4 phases/K-tile:
//   {ds_read quadrant frags; issue 1 half-tile prefetch; [counted vmcnt];
//    s_barrier; setprio(1) 16xMFMA setprio(0)}
// Waits: vmcnt(2) end-of-P1 (retires this tile's Ah1+Bh1, leaves next Ah0),
//        vmcnt(4) end-of-P4 (retires next Ah0+Bh0, leaves next Ah1+Bh1).
// Never drains mid-loop; final K-tile peeled with one vmcnt(0).
// Safety: reads at phase p covered by wait+barrier ending phase p-1 (per-wave
// vmcnt + joint barrier => all waves' slices landed); WAR at buffer swap
// covered by P4 barrier (prefetch targets the buffer last read 2 phases ago).
// LDS XOR swizzle unit(r,kc)=(r*8+kc)^(r&7), inverse-swizzled global source.
// ---------------------------------------------------------------------------
#define G8P_READ_A(mh)                                                        \
    _Pragma("unroll") for (int f = 0; f < 4; ++f) {                           \
        const int r_ = ((mh) * 4 + f) * 32 + wm * 16 + lr;                    \
        _Pragma("unroll") for (int kk = 0; kk < 2; ++kk) {                    \
            const int u_ = (r_ * 8 + kk * 4 + lg) ^ (r_ & 7);                 \
            areg[f][kk] = ((const bf16x8*)Ac)[u_];                            \
        }                                                                     \
    }

#define G8P_READ_B(nh)                                                        \
    _Pragma("unroll") for (int g = 0; g < 2; ++g) {                           \
        const int r_ = ((nh) * 2 + g) * 64 + wn * 16 + lr;                    \
        _Pragma("unroll") for (int kk = 0; kk < 2; ++kk) {                    \
            const int u_ = (r_ * 8 + kk * 4 + lg) ^ (r_ & 7);                 \
            breg[nh][g][kk] = ((const bf16x8*)Bc)[u_];                        \
        }                                                                     \
    }

#define G8P_QUAD(mh, nh)                                                      \
    _Pragma("unroll") for (int f = 0; f < 4; ++f)                             \
    _Pragma("unroll") for (int g = 0; g < 2; ++g)                             \
    _Pragma("unroll") for (int kk = 0; kk < 2; ++kk)                          \
        acc[(mh) * 4 + f][(nh) * 2 + g] =                                     \
            __builtin_amdgcn_mfma_f32_16x16x32_bf16(                          \
                areg[f][kk], breg[nh][g][kk],                                 \
                acc[(mh) * 4 + f][(nh) * 2 + g], 0, 0, 0);

template<bool GELU, int LDC, int NTX, int KTOT>
__global__ __launch_bounds__(512, 2)
void gemm8p(const short* __restrict__ A, const short* __restrict__ Bw,
            const int* __restrict__ cnt, void* __restrict__ Cout) {
    // fixed geometry: BM=BN=256, WM=2, WN=4 -> MF=8, NF=4, 16 MFMA/phase
    constexpr int A_SH = 16384;            // shorts per A tile (256*64)
    constexpr int SEG = 32768;             // shorts per LDS buffer (A+B)
    constexpr int KT = KTOT / 64;

    __shared__ __align__(16) short lds[2 * SEG];

    // bijective XCD swizzle (grid = NTX*MT256, divisible by 8)
    const int lin = blockIdx.x;
    constexpr int CPX = (NTX * MT256) / 8;
    const int wg = (lin & 7) * CPX + (lin >> 3);
    const int mt = wg / NTX;
    const int nt = wg - mt * NTX;

    int row0, rend, e;
    tile_map256(cnt, mt, row0, rend, e);
    if (e < 0) return;
    const int n0 = nt * 256;
    const short* Be = Bw + (size_t)e * ((size_t)F_DIM * H_DIM);

    const int tid = threadIdx.x;
    const int lane = tid & 63;
    const int lr = lane & 15;
    const int lg = lane >> 4;
    const int w = tid >> 6;
    const int wm = w >> 2;         // 0..1
    const int wn = w & 3;          // 0..3

    // inverse-swizzled staging sources (half h = pointers 2h, 2h+1)
    const short* ag[4];
    const short* bg[4];
#pragma unroll
    for (int p = 0; p < 4; ++p) {
        int s = p * 512 + tid;
        int r = s >> 3;
        int kc = (s & 7) ^ (r & 7);
        int grow = row0 + r;
        if (grow >= T_TOK) grow = T_TOK - 1;
        ag[p] = A + (size_t)grow * KTOT + kc * 8;
        bg[p] = Be + (size_t)(n0 + r) * KTOT + kc * 8;
    }

    f32x4 acc[8][4];
#pragma unroll
    for (int i = 0; i < 8; ++i)
#pragma unroll
        for (int j = 0; j < 4; ++j) acc[i][j] = (f32x4){0.f, 0.f, 0.f, 0.f};
    bf16x8 areg[4][2];
    bf16x8 breg[2][2][2];

    // ---- prologue: stage tile 0, FIFO order [Ah0, Bh0, Ah1, Bh1]
    {
        short* An = lds;
        short* Bn = lds + A_SH;
        gload16(ag[0], An + (0 * 512 + tid) * 8); ag[0] += 64;
        gload16(ag[1], An + (1 * 512 + tid) * 8); ag[1] += 64;
        gload16(bg[0], Bn + (0 * 512 + tid) * 8); bg[0] += 64;
        gload16(bg[1], Bn + (1 * 512 + tid) * 8); bg[1] += 64;
        gload16(ag[2], An + (2 * 512 + tid) * 8); ag[2] += 64;
        gload16(ag[3], An + (3 * 512 + tid) * 8); ag[3] += 64;
        gload16(bg[2], Bn + (2 * 512 + tid) * 8); bg[2] += 64;
        gload16(bg[3], Bn + (3 * 512 + tid) * 8); bg[3] += 64;
    }
    vmwait<4>();   // Ah0,Bh0 landed; Ah1,Bh1 may be in flight
    bar();

    int cur = 0;
    // Main loop: always prefetches tile kt+1 -> counted waits are exact.
    for (int kt = 0; kt < KT - 1; ++kt) {
        const short* Ac = lds + cur * SEG;
        const short* Bc = Ac + A_SH;
        short* An = lds + (cur ^ 1) * SEG;
        short* Bn = An + A_SH;

        // ---- P1: q(0,0); issue next Ah0; wait retires this tile's Ah1+Bh1
        G8P_READ_A(0)
        G8P_READ_B(0)
        gload16(ag[0], An + (0 * 512 + tid) * 8); ag[0] += 64;
        gload16(ag[1], An + (1 * 512 + tid) * 8); ag[1] += 64;
        vmwait<2>();
        bar();
        __builtin_amdgcn_s_setprio(1);
        G8P_QUAD(0, 0)
        __builtin_amdgcn_s_setprio(0);

        // ---- P2: q(0,1); issue next Bh0
        G8P_READ_B(1)
        gload16(bg[0], Bn + (0 * 512 + tid) * 8); bg[0] += 64;
        gload16(bg[1], Bn + (1 * 512 + tid) * 8); bg[1] += 64;
        bar();
        __builtin_amdgcn_s_setprio(1);
        G8P_QUAD(0, 1)
        __builtin_amdgcn_s_setprio(0);

        // ---- P3: q(1,1); issue next Ah1
        G8P_READ_A(1)
        gload16(ag[2], An + (2 * 512 + tid) * 8); ag[2] += 64;
        gload16(ag[3], An + (3 * 512 + tid) * 8); ag[3] += 64;
        bar();
        __builtin_amdgcn_s_setprio(1);
        G8P_QUAD(1, 1)
        __builtin_amdgcn_s_setprio(0);

        // ---- P4: q(1,0) (reuses areg1+breg0); issue next Bh1; end wait
        gload16(bg[2], Bn + (2 * 512 + tid) * 8); bg[2] += 64;
        gload16(bg[3], Bn + (3 * 512 + tid) * 8); bg[3] += 64;
        vmwait<4>();   // next Ah0+Bh0 landed; next Ah1+Bh1 in flight
        bar();
        __builtin_amdgcn_s_setprio(1);
        G8P_QUAD(1, 0)
        __builtin_amdgcn_s_setprio(0);
        cur ^= 1;
    }

    // ---- peeled final K-tile: no prefetch; one full drain before h1 halves
    {
        const short* Ac = lds + cur * SEG;
        const short* Bc = Ac + A_SH;
        G8P_READ_A(0)
        G8P_READ_B(0)
        G8P_QUAD(0, 0)
        vmwait<0>();           // drain this tile's in-flight Ah1/Bh1
        bar();
        G8P_READ_B(1)
        G8P_QUAD(0, 1)
        G8P_READ_A(1)
        G8P_QUAD(1, 1)
        G8P_QUAD(1, 0)
    }

    // ---- epilogue
#pragma unroll
    for (int f = 0; f < 8; ++f) {
#pragma unroll
        for (int g = 0; g < 4; ++g) {
            const int gcol = n0 + g * 64 + wn * 16 + lr;
#pragma unroll
            for (int rr = 0; rr < 4; ++rr) {
                const int grow = row0 + f * 32 + wm * 16 + lg * 4 + rr;
                if (grow < rend) {
                    float v = acc[f][g][rr];
                    if constexpr (GELU) {
                        ((short*)Cout)[(size_t)grow * LDC + gcol] = f2bf(fast_gelu(v));
                    } else {
                        ((float*)Cout)[(size_t)grow * LDC + gcol] = v;
                    }
                }
            }
        }
    }
}

// ---------------------------------------------------------------------------
// Round-1 fallback kernels (only used if ws too small for bf16 prep buffers)
// ---------------------------------------------------------------------------
__global__ __launch_bounds__(NT)
void gemm1_kernel(const float* __restrict__ X, const float* __restrict__ W1,
                  const int* __restrict__ cnt, short* __restrict__ act) {
    __shared__ short Alds[128 * 64];
    __shared__ short Blds[128 * 64];

    int row0, rend, e;
    tile_map128(cnt, blockIdx.y, row0, rend, e);
    if (e < 0) return;

    const int n0 = blockIdx.x * 128;
    const float* W = W1 + (size_t)e * H_DIM * F_DIM;

    const int tid = threadIdx.x;
    const int lane = tid & 63;
    const int w = tid >> 6;
    const int wr = (w >> 1) * 64;
    const int wc = (w & 1) * 64;
    const int lr = lane & 15;
    const int lg = lane >> 4;

    const int a_r0 = tid >> 3;
    const int a_kc = tid & 7;
    const int b_n = tid & 127;
    const int b_kg = (tid >> 7) * 8;

    f32x4 acc[4][4];
#pragma unroll
    for (int i = 0; i < 4; ++i)
#pragma unroll
        for (int j = 0; j < 4; ++j) acc[i][j] = (f32x4){0.f, 0.f, 0.f, 0.f};

    for (int kt = 0; kt < H_DIM / 64; ++kt) {
        const int k0 = kt * 64;
#pragma unroll
        for (int p = 0; p < 4; ++p) {
            int r = a_r0 + 32 * p;
            int grow = row0 + r;
            if (grow > T_TOK - 1) grow = T_TOK - 1;
            const float* src = X + (size_t)grow * H_DIM + k0 + a_kc * 8;
            f32x4 f0 = *(const f32x4*)src;
            f32x4 f1 = *(const f32x4*)(src + 4);
            bf16x8 v;
            v[0] = f2bf(f0[0]); v[1] = f2bf(f0[1]); v[2] = f2bf(f0[2]); v[3] = f2bf(f0[3]);
            v[4] = f2bf(f1[0]); v[5] = f2bf(f1[1]); v[6] = f2bf(f1[2]); v[7] = f2bf(f1[3]);
            ((bf16x8*)Alds)[(r * 8 + a_kc) ^ (r & 7)] = v;
        }
#pragma unroll
        for (int p = 0; p < 4; ++p) {
            int kb = p * 16 + b_kg;
            const float* src = W + (size_t)(k0 + kb) * F_DIM + n0 + b_n;
            bf16x8 v;
#pragma unroll
            for (int j = 0; j < 8; ++j) v[j] = f2bf(src[(size_t)j * F_DIM]);
            ((bf16x8*)Blds)[(b_n * 8 + (kb >> 3)) ^ (b_n & 7)] = v;
        }
        __syncthreads();
#pragma unroll
        for (int kk = 0; kk < 2; ++kk) {
            bf16x8 af[4], bfr[4];
#pragma unroll
            for (int fm = 0; fm < 4; ++fm) {
                int r = wr + fm * 16 + lr;
                af[fm] = ((bf16x8*)Alds)[(r * 8 + kk * 4 + lg) ^ (r & 7)];
            }
#pragma unroll
            for (int fn = 0; fn < 4; ++fn) {
                int n = wc + fn * 16 + lr;
                bfr[fn] = ((bf16x8*)Blds)[(n * 8 + kk * 4 + lg) ^ (n & 7)];
            }
#pragma unroll
            for (int fm = 0; fm < 4; ++fm)
#pragma unroll
                for (int fn = 0; fn < 4; ++fn)
                    acc[fm][fn] = __builtin_amdgcn_mfma_f32_16x16x32_bf16(
                        af[fm], bfr[fn], acc[fm][fn], 0, 0, 0);
        }
        __syncthreads();
    }

#pragma unroll
    for (int fm = 0; fm < 4; ++fm)
#pragma unroll
        for (int fn = 0; fn < 4; ++fn) {
            int gcol = n0 + wc + fn * 16 + lr;
#pragma unroll
            for (int rr = 0; rr < 4; ++rr) {
                int grow = row0 + wr + fm * 16 + lg * 4 + rr;
                if (grow < rend)
                    act[(size_t)grow * F_DIM + gcol] = f2bf(fast_gelu(acc[fm][fn][rr]));
            }
        }
}

__global__ __launch_bounds__(NT)
void gemm2_kernel(const short* __restrict__ ACT, const float* __restrict__ W2,
                  const int* __restrict__ cnt, float* __restrict__ out) {
    __shared__ short Alds[128 * 64];
    __shared__ short Blds[128 * 64];

    int row0, rend, e;
    tile_map128(cnt, blockIdx.y, row0, rend, e);
    if (e < 0) return;

    const int n0 = blockIdx.x * 128;
    const float* W = W2 + (size_t)e * F_DIM * H_DIM;

    const int tid = threadIdx.x;
    const int lane = tid & 63;
    const int w = tid >> 6;
    const int wr = (w >> 1) * 64;
    const int wc = (w & 1) * 64;
    const int lr = lane & 15;
    const int lg = lane >> 4;

    const int a_r0 = tid >> 3;
    const int a_kc = tid & 7;
    const int b_n = tid & 127;
    const int b_kg = (tid >> 7) * 8;

    f32x4 acc[4][4];
#pragma unroll
    for (int i = 0; i < 4; ++i)
#pragma unroll
        for (int j = 0; j < 4; ++j) acc[i][j] = (f32x4){0.f, 0.f, 0.f, 0.f};

    for (int kt = 0; kt < F_DIM / 64; ++kt) {
        const int k0 = kt * 64;
#pragma unroll
        for (int p = 0; p < 4; ++p) {
            int r = a_r0 + 32 * p;
            int grow = row0 + r;
            if (grow > T_TOK - 1) grow = T_TOK - 1;
            bf16x8 v = *(const bf16x8*)(ACT + (size_t)grow * F_DIM + k0 + a_kc * 8);
            ((bf16x8*)Alds)[(r * 8 + a_kc) ^ (r & 7)] = v;
        }
#pragma unroll
        for (int p = 0; p < 4; ++p) {
            int kb = p * 16 + b_kg;
            const float* src = W + (size_t)(k0 + kb) * H_DIM + n0 + b_n;
            bf16x8 v;
#pragma unroll
            for (int j = 0; j < 8; ++j) v[j] = f2bf(src[(size_t)j * H_DIM]);
            ((bf16x8*)Blds)[(b_n * 8 + (kb >> 3)) ^ (b_n & 7)] = v;
        }
        __syncthreads();
#pragma unroll
        for (int kk = 0; kk < 2; ++kk) {
            bf16x8 af[4], bfr[4];
#pragma unroll
            for (int fm = 0; fm < 4; ++fm) {
                int r = wr + fm * 16 + lr;
                af[fm] = ((bf16x8*)Alds)[(r * 8 + kk * 4 + lg) ^ (r & 7)];
            }
#pragma unroll
            for (int fn = 0; fn < 4; ++fn) {
                int n = wc + fn * 16 + lr;
                bfr[fn] = ((bf16x8*)Blds)[(n * 8 + kk * 4 + lg) ^ (n & 7)];
            }
#pragma unroll
            for (int fm = 0; fm < 4; ++fm)
#pragma unroll
                for (int fn = 0; fn < 4; ++fn)
                    acc[fm][fn] = __builtin_amdgcn_mfma_f32_16x16x32_bf16(
                        af[fm], bfr[fn], acc[fm][fn], 0, 0, 0);
        }
        __syncthreads();
    }

#pragma unroll
    for (int fm = 0; fm < 4; ++fm)
#pragma unroll
        for (int fn = 0; fn < 4; ++fn) {
            int gcol = n0 + wc + fn * 16 + lr;
#pragma unroll
            for (int rr = 0; rr < 4; ++rr) {
                int grow = row0 + wr + fm * 16 + lg * 4 + rr;
                if (grow < rend) out[(size_t)grow * H_DIM + gcol] = acc[fm][fn][rr];
            }
        }
}

extern "C" void kernel_launch(void* const* d_in, const int* in_sizes, int n_in,
                              void* d_out, int out_size, void* d_ws, size_t ws_size,
                              hipStream_t stream) {
    const float* x  = (const float*)d_in[0];
    const float* w1 = (const float*)d_in[1];
    const float* w2 = (const float*)d_in[2];
    const int* cnt  = (const int*)d_in[3];
    float* out = (float*)d_out;

    const size_t ACT_B = (size_t)T_TOK * F_DIM * 2;              // 128 MiB
    const size_t WT_B  = (size_t)E_NUM * F_DIM * H_DIM * 2;      //  64 MiB
    const size_t XB_B  = (size_t)T_TOK * H_DIM * 2;              //  32 MiB

    if (ws_size >= ACT_B + WT_B + XB_B) {
        short* act = (short*)d_ws;
        short* wt  = (short*)((char*)d_ws + ACT_B);
        short* xb  = (short*)((char*)d_ws + ACT_B + WT_B);

        cvt_x_kernel<<<2048, NT, 0, stream>>>(x, xb, T_TOK * H_DIM / 8);
        transpose_cvt<<<dim3(F_DIM / 64, H_DIM / 64, E_NUM), NT, 0, stream>>>(
            w1, wt, H_DIM, F_DIM);
        gemm8p<true, F_DIM, 16, H_DIM>
            <<<16 * MT256, 512, 0, stream>>>(xb, wt, cnt, (void*)act);
        transpose_cvt<<<dim3(H_DIM / 64, F_DIM / 64, E_NUM), NT, 0, stream>>>(
            w2, wt, F_DIM, H_DIM);
        gemm8p<false, H_DIM, 4, F_DIM>
            <<<4 * MT256, 512, 0, stream>>>(act, wt, cnt, (void*)out);
    } else if (ws_size >= ACT_B) {
        short* act = (short*)d_ws;
        gemm1_kernel<<<dim3(F_DIM / 128, MT_MAX), NT, 0, stream>>>(x, w1, cnt, act);
        gemm2_kernel<<<dim3(H_DIM / 128, MT_MAX), NT, 0, stream>>>(act, w2, cnt, out);
    }
}

// Round 6
// 465.685 us; speedup vs baseline: 1.5232x; 1.0207x over previous
//
#include <hip/hip_runtime.h>
#include <hip/hip_bf16.h>

// Problem constants (match reference)
#define E_NUM 8
#define H_DIM 1024
#define F_DIM 4096
#define T_TOK 16384

#define NT 256
#define MT_MAX (T_TOK / 128 + E_NUM)    // 136 worst-case 128-row M tiles (fallback)
#define MT256 (T_TOK / 256 + E_NUM)     // 72 worst-case 256-row M tiles

typedef __attribute__((ext_vector_type(8))) short bf16x8;
typedef __attribute__((ext_vector_type(4))) float f32x4;

__device__ __forceinline__ short f2bf(float f) {
    unsigned u = __builtin_bit_cast(unsigned, f);
    u += 0x7FFFu + ((u >> 16) & 1u);
    return (short)(u >> 16);
}

__device__ __forceinline__ float exp2_fast(float a) {
#if __has_builtin(__builtin_amdgcn_exp2f)
    return __builtin_amdgcn_exp2f(a);
#else
    return exp2f(a);
#endif
}
__device__ __forceinline__ float rcp_fast(float a) {
#if __has_builtin(__builtin_amdgcn_rcpf)
    return __builtin_amdgcn_rcpf(a);
#else
    return 1.0f / a;
#endif
}

// tanh-form gelu: max |err| vs exact ~1e-3 (negligible vs bf16 noise)
__device__ __forceinline__ float fast_gelu(float x) {
    float x2 = x * x;
    float y = x * (0.7978845608f + 0.0356774081f * x2);
    float z = exp2_fast(y * 2.8853900817779268f);   // e^{2y}
    float r = rcp_fast(z + 1.0f);
    return x * (1.0f - r);
}

__device__ __forceinline__ void gload16(const void* g, void* l) {
    __builtin_amdgcn_global_load_lds(
        (const __attribute__((address_space(1))) void*)g,
        (__attribute__((address_space(3))) void*)l, 16, 0, 0);
}

template<int N>
__device__ __forceinline__ void vmwait() {
    if constexpr (N == 0) asm volatile("s_waitcnt vmcnt(0)" ::: "memory");
    else if constexpr (N == 1) asm volatile("s_waitcnt vmcnt(1)" ::: "memory");
    else if constexpr (N == 2) asm volatile("s_waitcnt vmcnt(2)" ::: "memory");
    else if constexpr (N == 3) asm volatile("s_waitcnt vmcnt(3)" ::: "memory");
    else if constexpr (N == 4) asm volatile("s_waitcnt vmcnt(4)" ::: "memory");
}

// raw barrier with compiler memory-ordering (no waitcnt insertion)
__device__ __forceinline__ void bar() {
    asm volatile("s_barrier" ::: "memory");
}

__device__ __forceinline__ void tile_map128(const int* __restrict__ cnt, int mt,
                                            int& row0, int& rend, int& e_out) {
    int acc = 0, off = 0;
    e_out = -1;
    for (int i = 0; i < E_NUM; ++i) {
        int c = cnt[i];
        int nti = (c + 127) >> 7;
        if (mt < acc + nti) {
            e_out = i; row0 = off + (mt - acc) * 128; rend = off + c; return;
        }
        acc += nti; off += c;
    }
}

__device__ __forceinline__ void tile_map256(const int* __restrict__ cnt, int mt,
                                            int& row0, int& rend, int& e_out) {
    int acc = 0, off = 0;
    e_out = -1;
    for (int i = 0; i < E_NUM; ++i) {
        int c = cnt[i];
        int nti = (c + 255) >> 8;
        if (mt < acc + nti) {
            e_out = i; row0 = off + (mt - acc) * 256; rend = off + c; return;
        }
        acc += nti; off += c;
    }
}

// ---------------------------------------------------------------------------
// Prep kernels
// ---------------------------------------------------------------------------
__global__ __launch_bounds__(NT)
void cvt_x_kernel(const float* __restrict__ in, short* __restrict__ out, int n8) {
    int i = blockIdx.x * blockDim.x + threadIdx.x;
    const int stride = gridDim.x * blockDim.x;
    for (; i < n8; i += stride) {
        f32x4 f0 = ((const f32x4*)in)[(size_t)i * 2];
        f32x4 f1 = ((const f32x4*)in)[(size_t)i * 2 + 1];
        bf16x8 v;
        v[0] = f2bf(f0[0]); v[1] = f2bf(f0[1]); v[2] = f2bf(f0[2]); v[3] = f2bf(f0[3]);
        v[4] = f2bf(f1[0]); v[5] = f2bf(f1[1]); v[6] = f2bf(f1[2]); v[7] = f2bf(f1[3]);
        ((bf16x8*)out)[i] = v;
    }
}

__global__ __launch_bounds__(NT)
void transpose_cvt(const float* __restrict__ in, short* __restrict__ out,
                   int R, int C) {
    __shared__ short tb[64][72];
    const int e = blockIdx.z;
    const float* ine = in + (size_t)e * R * C;
    short* oute = out + (size_t)e * R * C;
    const int c0 = blockIdx.x * 64, r0 = blockIdx.y * 64;
    const int t = threadIdx.x;
    const int rl = t >> 4, cl = (t & 15) * 4;
#pragma unroll
    for (int p = 0; p < 4; ++p) {
        int r = rl + p * 16;
        f32x4 f = *(const f32x4*)(ine + (size_t)(r0 + r) * C + c0 + cl);
#pragma unroll
        for (int j = 0; j < 4; ++j) tb[cl + j][r] = f2bf(f[j]);
    }
    __syncthreads();
    const int c2 = t >> 3, rc = (t & 7) * 8;
#pragma unroll
    for (int p = 0; p < 2; ++p) {
        int c = c2 + p * 32;
        bf16x8 v = *(const bf16x8*)&tb[c][rc];
        *(bf16x8*)(oute + (size_t)(c0 + c) * R + r0 + rc) = v;
    }
}

// ---------------------------------------------------------------------------
// 8-wave grouped GEMM, 256x256 tile, BK=64, 4 phases/K-tile.
// Issue order per iter k (for tile k+1): P1->Ah0', P2->Bh0', P3->Bh1', P4->Ah1'
// Need order for tile k: A0@P1, B1@P2, A1@P3, B0'@P4 (pre-read for next P1).
// Per-wave FIFO ledger (items = 2 gload16 each), steady state:
//   enter P1: [Bh1_k, Ah1_k]            +Ah0' -> wait vmcnt(4) retires Bh1_k
//   enter P2: [Ah1_k, Ah0']             +Bh0' -> wait vmcnt(4) retires Ah1_k
//   enter P3: [Ah0', Bh0']              +Bh1' -> no wait
//   enter P4: [Ah0', Bh0', Bh1']        +Ah1' -> wait vmcnt(4) retires Ah0',Bh0'
// Every wait's target was issued >=2 phases earlier (latency hidden).
// Final K-tile peeled: pP1 waits vmcnt(2) (Bh1), pP2 waits vmcnt(0) (Ah1).
// LDS XOR swizzle unit(r,kc)=(r*8+kc)^(r&7); inverse-swizzled global source,
// linear global_load_lds dest (both-sides rule).
// ---------------------------------------------------------------------------
#define G8P_READ_A(mh)                                                        \
    _Pragma("unroll") for (int f = 0; f < 4; ++f) {                           \
        const int r_ = ((mh) * 4 + f) * 32 + wm * 16 + lr;                    \
        _Pragma("unroll") for (int kk = 0; kk < 2; ++kk) {                    \
            const int u_ = (r_ * 8 + kk * 4 + lg) ^ (r_ & 7);                 \
            areg[f][kk] = ((const bf16x8*)Ac)[u_];                            \
        }                                                                     \
    }

#define G8P_READ_B(nh, BPTR)                                                  \
    _Pragma("unroll") for (int g = 0; g < 2; ++g) {                           \
        const int r_ = ((nh) * 2 + g) * 64 + wn * 16 + lr;                    \
        _Pragma("unroll") for (int kk = 0; kk < 2; ++kk) {                    \
            const int u_ = (r_ * 8 + kk * 4 + lg) ^ (r_ & 7);                 \
            breg[nh][g][kk] = ((const bf16x8*)(BPTR))[u_];                    \
        }                                                                     \
    }

#define G8P_QUAD(mh, nh)                                                      \
    _Pragma("unroll") for (int f = 0; f < 4; ++f)                             \
    _Pragma("unroll") for (int g = 0; g < 2; ++g)                             \
    _Pragma("unroll") for (int kk = 0; kk < 2; ++kk)                          \
        acc[(mh) * 4 + f][(nh) * 2 + g] =                                     \
            __builtin_amdgcn_mfma_f32_16x16x32_bf16(                          \
                areg[f][kk], breg[nh][g][kk],                                 \
                acc[(mh) * 4 + f][(nh) * 2 + g], 0, 0, 0);

template<bool GELU, int LDC, int NTX, int KTOT>
__global__ __launch_bounds__(512, 2)
void gemm8p(const short* __restrict__ A, const short* __restrict__ Bw,
            const int* __restrict__ cnt, void* __restrict__ Cout) {
    // fixed geometry: BM=BN=256, WM=2, WN=4 -> MF=8, NF=4, 16 MFMA/phase
    constexpr int A_SH = 16384;            // shorts per A tile (256*64)
    constexpr int SEG = 32768;             // shorts per LDS buffer (A+B)
    constexpr int KT = KTOT / 64;

    __shared__ __align__(16) short lds[2 * SEG];

    // bijective XCD swizzle (grid = NTX*MT256, divisible by 8)
    const int lin = blockIdx.x;
    constexpr int CPX = (NTX * MT256) / 8;
    const int wg = (lin & 7) * CPX + (lin >> 3);
    const int mt = wg / NTX;
    const int nt = wg - mt * NTX;

    int row0, rend, e;
    tile_map256(cnt, mt, row0, rend, e);
    if (e < 0) return;
    const int n0 = nt * 256;
    const short* Be = Bw + (size_t)e * ((size_t)F_DIM * H_DIM);

    const int tid = threadIdx.x;
    const int lane = tid & 63;
    const int lr = lane & 15;
    const int lg = lane >> 4;
    const int w = tid >> 6;
    const int wm = w >> 2;         // 0..1
    const int wn = w & 3;          // 0..3

    // inverse-swizzled staging sources (half h = pointers 2h, 2h+1)
    const short* ag[4];
    const short* bg[4];
#pragma unroll
    for (int p = 0; p < 4; ++p) {
        int s = p * 512 + tid;
        int r = s >> 3;
        int kc = (s & 7) ^ (r & 7);
        int grow = row0 + r;
        if (grow >= T_TOK) grow = T_TOK - 1;
        ag[p] = A + (size_t)grow * KTOT + kc * 8;
        bg[p] = Be + (size_t)(n0 + r) * KTOT + kc * 8;
    }

    f32x4 acc[8][4];
#pragma unroll
    for (int i = 0; i < 8; ++i)
#pragma unroll
        for (int j = 0; j < 4; ++j) acc[i][j] = (f32x4){0.f, 0.f, 0.f, 0.f};
    bf16x8 areg[4][2];
    bf16x8 breg[2][2][2];

    // ---- prologue: stage tile 0, FIFO order [Ah0, Bh0, Bh1, Ah1]
    {
        short* An = lds;
        short* Bn = lds + A_SH;
        gload16(ag[0], An + (0 * 512 + tid) * 8); ag[0] += 64;
        gload16(ag[1], An + (1 * 512 + tid) * 8); ag[1] += 64;
        gload16(bg[0], Bn + (0 * 512 + tid) * 8); bg[0] += 64;
        gload16(bg[1], Bn + (1 * 512 + tid) * 8); bg[1] += 64;
        gload16(bg[2], Bn + (2 * 512 + tid) * 8); bg[2] += 64;
        gload16(bg[3], Bn + (3 * 512 + tid) * 8); bg[3] += 64;
        gload16(ag[2], An + (2 * 512 + tid) * 8); ag[2] += 64;
        gload16(ag[3], An + (3 * 512 + tid) * 8); ag[3] += 64;
    }
    vmwait<4>();   // Ah0,Bh0 landed; Bh1,Ah1 may be in flight
    bar();
    G8P_READ_B(0, lds + A_SH)   // pre-read B0 of tile 0

    int cur = 0;
    // Main loop: always prefetches tile kt+1 -> counted waits are exact.
    for (int kt = 0; kt < KT - 1; ++kt) {
        const short* Ac = lds + cur * SEG;
        const short* Bc = Ac + A_SH;
        short* An = lds + (cur ^ 1) * SEG;
        short* Bn = An + A_SH;

        // ---- P1: read A0; issue next Ah0; wait retires this tile's Bh1
        G8P_READ_A(0)
        gload16(ag[0], An + (0 * 512 + tid) * 8); ag[0] += 64;
        gload16(ag[1], An + (1 * 512 + tid) * 8); ag[1] += 64;
        vmwait<4>();
        bar();
        __builtin_amdgcn_s_setprio(1);
        G8P_QUAD(0, 0)
        __builtin_amdgcn_s_setprio(0);

        // ---- P2: read B1; issue next Bh0; wait retires this tile's Ah1
        G8P_READ_B(1, Bc)
        gload16(bg[0], Bn + (0 * 512 + tid) * 8); bg[0] += 64;
        gload16(bg[1], Bn + (1 * 512 + tid) * 8); bg[1] += 64;
        vmwait<4>();
        bar();
        __builtin_amdgcn_s_setprio(1);
        G8P_QUAD(0, 1)
        __builtin_amdgcn_s_setprio(0);

        // ---- P3: read A1; issue next Bh1; no wait
        G8P_READ_A(1)
        gload16(bg[2], Bn + (2 * 512 + tid) * 8); bg[2] += 64;
        gload16(bg[3], Bn + (3 * 512 + tid) * 8); bg[3] += 64;
        bar();
        __builtin_amdgcn_s_setprio(1);
        G8P_QUAD(1, 1)
        __builtin_amdgcn_s_setprio(0);

        // ---- P4: issue next Ah1; wait retires next Ah0+Bh0; pre-read next B0
        gload16(ag[2], An + (2 * 512 + tid) * 8); ag[2] += 64;
        gload16(ag[3], An + (3 * 512 + tid) * 8); ag[3] += 64;
        vmwait<4>();
        bar();
        __builtin_amdgcn_s_setprio(1);
        G8P_QUAD(1, 0)
        __builtin_amdgcn_s_setprio(0);
        G8P_READ_B(0, Bn)
        cur ^= 1;
    }

    // ---- peeled final K-tile: queue holds [Bh1, Ah1] of this tile
    {
        const short* Ac = lds + cur * SEG;
        const short* Bc = Ac + A_SH;
        G8P_READ_A(0)
        vmwait<2>();   // retire Bh1
        bar();
        G8P_QUAD(0, 0)
        G8P_READ_B(1, Bc)
        vmwait<0>();   // retire Ah1
        bar();
        G8P_QUAD(0, 1)
        G8P_READ_A(1)
        G8P_QUAD(1, 1)
        G8P_QUAD(1, 0)
    }

    // ---- epilogue
#pragma unroll
    for (int f = 0; f < 8; ++f) {
#pragma unroll
        for (int g = 0; g < 4; ++g) {
            const int gcol = n0 + g * 64 + wn * 16 + lr;
#pragma unroll
            for (int rr = 0; rr < 4; ++rr) {
                const int grow = row0 + f * 32 + wm * 16 + lg * 4 + rr;
                if (grow < rend) {
                    float v = acc[f][g][rr];
                    if constexpr (GELU) {
                        ((short*)Cout)[(size_t)grow * LDC + gcol] = f2bf(fast_gelu(v));
                    } else {
                        ((float*)Cout)[(size_t)grow * LDC + gcol] = v;
                    }
                }
            }
        }
    }
}

// ---------------------------------------------------------------------------
// Round-1 fallback kernels (only used if ws too small for bf16 prep buffers)
// ---------------------------------------------------------------------------
__global__ __launch_bounds__(NT)
void gemm1_kernel(const float* __restrict__ X, const float* __restrict__ W1,
                  const int* __restrict__ cnt, short* __restrict__ act) {
    __shared__ short Alds[128 * 64];
    __shared__ short Blds[128 * 64];

    int row0, rend, e;
    tile_map128(cnt, blockIdx.y, row0, rend, e);
    if (e < 0) return;

    const int n0 = blockIdx.x * 128;
    const float* W = W1 + (size_t)e * H_DIM * F_DIM;

    const int tid = threadIdx.x;
    const int lane = tid & 63;
    const int w = tid >> 6;
    const int wr = (w >> 1) * 64;
    const int wc = (w & 1) * 64;
    const int lr = lane & 15;
    const int lg = lane >> 4;

    const int a_r0 = tid >> 3;
    const int a_kc = tid & 7;
    const int b_n = tid & 127;
    const int b_kg = (tid >> 7) * 8;

    f32x4 acc[4][4];
#pragma unroll
    for (int i = 0; i < 4; ++i)
#pragma unroll
        for (int j = 0; j < 4; ++j) acc[i][j] = (f32x4){0.f, 0.f, 0.f, 0.f};

    for (int kt = 0; kt < H_DIM / 64; ++kt) {
        const int k0 = kt * 64;
#pragma unroll
        for (int p = 0; p < 4; ++p) {
            int r = a_r0 + 32 * p;
            int grow = row0 + r;
            if (grow > T_TOK - 1) grow = T_TOK - 1;
            const float* src = X + (size_t)grow * H_DIM + k0 + a_kc * 8;
            f32x4 f0 = *(const f32x4*)src;
            f32x4 f1 = *(const f32x4*)(src + 4);
            bf16x8 v;
            v[0] = f2bf(f0[0]); v[1] = f2bf(f0[1]); v[2] = f2bf(f0[2]); v[3] = f2bf(f0[3]);
            v[4] = f2bf(f1[0]); v[5] = f2bf(f1[1]); v[6] = f2bf(f1[2]); v[7] = f2bf(f1[3]);
            ((bf16x8*)Alds)[(r * 8 + a_kc) ^ (r & 7)] = v;
        }
#pragma unroll
        for (int p = 0; p < 4; ++p) {
            int kb = p * 16 + b_kg;
            const float* src = W + (size_t)(k0 + kb) * F_DIM + n0 + b_n;
            bf16x8 v;
#pragma unroll
            for (int j = 0; j < 8; ++j) v[j] = f2bf(src[(size_t)j * F_DIM]);
            ((bf16x8*)Blds)[(b_n * 8 + (kb >> 3)) ^ (b_n & 7)] = v;
        }
        __syncthreads();
#pragma unroll
        for (int kk = 0; kk < 2; ++kk) {
            bf16x8 af[4], bfr[4];
#pragma unroll
            for (int fm = 0; fm < 4; ++fm) {
                int r = wr + fm * 16 + lr;
                af[fm] = ((bf16x8*)Alds)[(r * 8 + kk * 4 + lg) ^ (r & 7)];
            }
#pragma unroll
            for (int fn = 0; fn < 4; ++fn) {
                int n = wc + fn * 16 + lr;
                bfr[fn] = ((bf16x8*)Blds)[(n * 8 + kk * 4 + lg) ^ (n & 7)];
            }
#pragma unroll
            for (int fm = 0; fm < 4; ++fm)
#pragma unroll
                for (int fn = 0; fn < 4; ++fn)
                    acc[fm][fn] = __builtin_amdgcn_mfma_f32_16x16x32_bf16(
                        af[fm], bfr[fn], acc[fm][fn], 0, 0, 0);
        }
        __syncthreads();
    }

#pragma unroll
    for (int fm = 0; fm < 4; ++fm)
#pragma unroll
        for (int fn = 0; fn < 4; ++fn) {
            int gcol = n0 + wc + fn * 16 + lr;
#pragma unroll
            for (int rr = 0; rr < 4; ++rr) {
                int grow = row0 + wr + fm * 16 + lg * 4 + rr;
                if (grow < rend)
                    act[(size_t)grow * F_DIM + gcol] = f2bf(fast_gelu(acc[fm][fn][rr]));
            }
        }
}

__global__ __launch_bounds__(NT)
void gemm2_kernel(const short* __restrict__ ACT, const float* __restrict__ W2,
                  const int* __restrict__ cnt, float* __restrict__ out) {
    __shared__ short Alds[128 * 64];
    __shared__ short Blds[128 * 64];

    int row0, rend, e;
    tile_map128(cnt, blockIdx.y, row0, rend, e);
    if (e < 0) return;

    const int n0 = blockIdx.x * 128;
    const float* W = W2 + (size_t)e * F_DIM * H_DIM;

    const int tid = threadIdx.x;
    const int lane = tid & 63;
    const int w = tid >> 6;
    const int wr = (w >> 1) * 64;
    const int wc = (w & 1) * 64;
    const int lr = lane & 15;
    const int lg = lane >> 4;

    const int a_r0 = tid >> 3;
    const int a_kc = tid & 7;
    const int b_n = tid & 127;
    const int b_kg = (tid >> 7) * 8;

    f32x4 acc[4][4];
#pragma unroll
    for (int i = 0; i < 4; ++i)
#pragma unroll
        for (int j = 0; j < 4; ++j) acc[i][j] = (f32x4){0.f, 0.f, 0.f, 0.f};

    for (int kt = 0; kt < F_DIM / 64; ++kt) {
        const int k0 = kt * 64;
#pragma unroll
        for (int p = 0; p < 4; ++p) {
            int r = a_r0 + 32 * p;
            int grow = row0 + r;
            if (grow > T_TOK - 1) grow = T_TOK - 1;
            bf16x8 v = *(const bf16x8*)(ACT + (size_t)grow * F_DIM + k0 + a_kc * 8);
            ((bf16x8*)Alds)[(r * 8 + a_kc) ^ (r & 7)] = v;
        }
#pragma unroll
        for (int p = 0; p < 4; ++p) {
            int kb = p * 16 + b_kg;
            const float* src = W + (size_t)(k0 + kb) * H_DIM + n0 + b_n;
            bf16x8 v;
#pragma unroll
            for (int j = 0; j < 8; ++j) v[j] = f2bf(src[(size_t)j * H_DIM]);
            ((bf16x8*)Blds)[(b_n * 8 + (kb >> 3)) ^ (b_n & 7)] = v;
        }
        __syncthreads();
#pragma unroll
        for (int kk = 0; kk < 2; ++kk) {
            bf16x8 af[4], bfr[4];
#pragma unroll
            for (int fm = 0; fm < 4; ++fm) {
                int r = wr + fm * 16 + lr;
                af[fm] = ((bf16x8*)Alds)[(r * 8 + kk * 4 + lg) ^ (r & 7)];
            }
#pragma unroll
            for (int fn = 0; fn < 4; ++fn) {
                int n = wc + fn * 16 + lr;
                bfr[fn] = ((bf16x8*)Blds)[(n * 8 + kk * 4 + lg) ^ (n & 7)];
            }
#pragma unroll
            for (int fm = 0; fm < 4; ++fm)
#pragma unroll
                for (int fn = 0; fn < 4; ++fn)
                    acc[fm][fn] = __builtin_amdgcn_mfma_f32_16x16x32_bf16(
                        af[fm], bfr[fn], acc[fm][fn], 0, 0, 0);
        }
        __syncthreads();
    }

#pragma unroll
    for (int fm = 0; fm < 4; ++fm)
#pragma unroll
        for (int fn = 0; fn < 4; ++fn) {
            int gcol = n0 + wc + fn * 16 + lr;
#pragma unroll
            for (int rr = 0; rr < 4; ++rr) {
                int grow = row0 + wr + fm * 16 + lg * 4 + rr;
                if (grow < rend) out[(size_t)grow * H_DIM + gcol] = acc[fm][fn][rr];
            }
        }
}

extern "C" void kernel_launch(void* const* d_in, const int* in_sizes, int n_in,
                              void* d_out, int out_size, void* d_ws, size_t ws_size,
                              hipStream_t stream) {
    const float* x  = (const float*)d_in[0];
    const float* w1 = (const float*)d_in[1];
    const float* w2 = (const float*)d_in[2];
    const int* cnt  = (const int*)d_in[3];
    float* out = (float*)d_out;

    const size_t ACT_B = (size_t)T_TOK * F_DIM * 2;              // 128 MiB
    const size_t WT_B  = (size_t)E_NUM * F_DIM * H_DIM * 2;      //  64 MiB
    const size_t XB_B  = (size_t)T_TOK * H_DIM * 2;              //  32 MiB

    if (ws_size >= ACT_B + WT_B + XB_B) {
        short* act = (short*)d_ws;
        short* wt  = (short*)((char*)d_ws + ACT_B);
        short* xb  = (short*)((char*)d_ws + ACT_B + WT_B);

        cvt_x_kernel<<<2048, NT, 0, stream>>>(x, xb, T_TOK * H_DIM / 8);
        transpose_cvt<<<dim3(F_DIM / 64, H_DIM / 64, E_NUM), NT, 0, stream>>>(
            w1, wt, H_DIM, F_DIM);
        gemm8p<true, F_DIM, 16, H_DIM>
            <<<16 * MT256, 512, 0, stream>>>(xb, wt, cnt, (void*)act);
        transpose_cvt<<<dim3(H_DIM / 64, F_DIM / 64, E_NUM), NT, 0, stream>>>(
            w2, wt, F_DIM, H_DIM);
        gemm8p<false, H_DIM, 4, F_DIM>
            <<<4 * MT256, 512, 0, stream>>>(act, wt, cnt, (void*)out);
    } else if (ws_size >= ACT_B) {
        short* act = (short*)d_ws;
        gemm1_kernel<<<dim3(F_DIM / 128, MT_MAX), NT, 0, stream>>>(x, w1, cnt, act);
        gemm2_kernel<<<dim3(H_DIM / 128, MT_MAX), NT, 0, stream>>>(act, w2, cnt, out);
    }
}